// Round 2
// baseline (3299.322 us; speedup 1.0000x reference)
//
#include <hip/hip_runtime.h>
#include <hip/hip_bf16.h>
#include <math.h>

namespace {

constexpr int kH     = 512;
constexpr int kL     = 1024;
constexpr int kB     = 64;
constexpr int kHalf  = 256;
constexpr int kV     = 32000;
constexpr int kTok   = kB * kL;     // 65536
constexpr int kChunk = 16384;       // tokens per FFN chunk (4 chunks)

// ---------------- positional weights: w[t] = sigmoid(pos_emb[t]·pos_w + pos_b)
__global__ void pos_kernel(const float* __restrict__ pos_emb,
                           const float* __restrict__ pos_w,
                           const float* __restrict__ pos_b,
                           float* __restrict__ wts)
{
  int t = blockIdx.x * blockDim.x + threadIdx.x;
  if (t >= kL) return;
  float z = pos_b[0];
#pragma unroll
  for (int p = 0; p < 16; ++p) z += pos_emb[t * 16 + p] * pos_w[p];
  wts[t] = 1.f / (1.f + expf(-z));
}

// ---------------- embedding gather: one wave per token
__global__ __launch_bounds__(256) void gather_embed(
    const int* __restrict__ seq, const float* __restrict__ embed,
    float* __restrict__ e_c, int tok0)
{
  const int wid  = threadIdx.x >> 6;
  const int lane = threadIdx.x & 63;
  const int ltok = blockIdx.x * 4 + wid;           // chunk-local token
  const int id   = seq[tok0 + ltok];
  const float4* src = (const float4*)(embed + (size_t)id * kH);
  float4* dst = (float4*)(e_c + (size_t)ltok * kH);
  dst[lane]      = src[lane];
  dst[lane + 64] = src[lane + 64];
}

// ---------------- fp32 GEMM: C[M,N] = A[M,K] @ B[K,N] + bias (+resid) (relu)
// 128x128 tile, BK=16, 256 threads, 8x8 micro-tile split as rows/cols {t*4, t*4+64}
template <bool RELU, bool RES>
__global__ __launch_bounds__(256) void gemm128(
    const float* __restrict__ A, const float* __restrict__ Bm,
    const float* __restrict__ bias, const float* __restrict__ resid,
    float* __restrict__ C, int M, int N, int K)
{
  __shared__ float As[16][128];
  __shared__ float Bs[16][128];
  const int tid = threadIdx.x;
  const int bm0 = blockIdx.y * 128;
  const int bn0 = blockIdx.x * 128;
  const int tm = tid >> 4, tn = tid & 15;

  float acc[8][8];
#pragma unroll
  for (int i = 0; i < 8; ++i)
#pragma unroll
    for (int j = 0; j < 8; ++j) acc[i][j] = 0.f;

  const int am = tid & 127;
  const int ak = (tid >> 7) * 8;                   // 0 or 8
  const float* Aptr = A + (size_t)(bm0 + am) * K + ak;
  const int bkr = tid >> 5;                        // 0..7
  const int bcg = (tid & 31) * 4;

  for (int k0 = 0; k0 < K; k0 += 16) {
    const float4 a0 = *(const float4*)(Aptr + k0);
    const float4 a1 = *(const float4*)(Aptr + k0 + 4);
    const float4 b0 = *(const float4*)(Bm + (size_t)(k0 + bkr) * N + bn0 + bcg);
    const float4 b1 = *(const float4*)(Bm + (size_t)(k0 + bkr + 8) * N + bn0 + bcg);
    __syncthreads();
    As[ak + 0][am] = a0.x; As[ak + 1][am] = a0.y;
    As[ak + 2][am] = a0.z; As[ak + 3][am] = a0.w;
    As[ak + 4][am] = a1.x; As[ak + 5][am] = a1.y;
    As[ak + 6][am] = a1.z; As[ak + 7][am] = a1.w;
    *(float4*)&Bs[bkr][bcg]     = b0;
    *(float4*)&Bs[bkr + 8][bcg] = b1;
    __syncthreads();
#pragma unroll
    for (int kk = 0; kk < 16; ++kk) {
      const float4 aA = *(const float4*)&As[kk][tm * 4];
      const float4 aB = *(const float4*)&As[kk][64 + tm * 4];
      const float4 bA = *(const float4*)&Bs[kk][tn * 4];
      const float4 bB = *(const float4*)&Bs[kk][64 + tn * 4];
      const float av[8] = {aA.x, aA.y, aA.z, aA.w, aB.x, aB.y, aB.z, aB.w};
      const float bv[8] = {bA.x, bA.y, bA.z, bA.w, bB.x, bB.y, bB.z, bB.w};
#pragma unroll
      for (int i = 0; i < 8; ++i)
#pragma unroll
        for (int j = 0; j < 8; ++j) acc[i][j] += av[i] * bv[j];
    }
  }

#pragma unroll
  for (int i = 0; i < 8; ++i) {
    const int row = bm0 + ((i < 4) ? (tm * 4 + i) : (64 + tm * 4 + i - 4));
#pragma unroll
    for (int hh = 0; hh < 2; ++hh) {
      const int n0 = bn0 + tn * 4 + hh * 64;
      const float4 bb = *(const float4*)(bias + n0);
      float vx = acc[i][hh * 4 + 0] + bb.x;
      float vy = acc[i][hh * 4 + 1] + bb.y;
      float vz = acc[i][hh * 4 + 2] + bb.z;
      float vw = acc[i][hh * 4 + 3] + bb.w;
      if (RES) {
        const float4 rr = *(const float4*)(resid + (size_t)row * N + n0);
        vx += rr.x; vy += rr.y; vz += rr.z; vw += rr.w;
      }
      if (RELU) {
        vx = fmaxf(vx, 0.f); vy = fmaxf(vy, 0.f);
        vz = fmaxf(vz, 0.f); vw = fmaxf(vw, 0.f);
      }
      float4 o; o.x = vx; o.y = vy; o.z = vz; o.w = vw;
      *(float4*)(C + (size_t)row * N + n0) = o;
    }
  }
}

// ---------------- LayerNorm in-place: one wave per token (512 elems)
__global__ __launch_bounds__(256) void ln_kernel(
    float* __restrict__ x, const float* __restrict__ g, const float* __restrict__ bta)
{
  const int wid  = threadIdx.x >> 6;
  const int lane = threadIdx.x & 63;
  const int ltok = blockIdx.x * 4 + wid;
  float* xp = x + (size_t)ltok * kH;
  const float4 v0 = *(const float4*)(xp + lane * 8);
  const float4 v1 = *(const float4*)(xp + lane * 8 + 4);
  float s  = v0.x + v0.y + v0.z + v0.w + v1.x + v1.y + v1.z + v1.w;
  float ss = v0.x * v0.x + v0.y * v0.y + v0.z * v0.z + v0.w * v0.w +
             v1.x * v1.x + v1.y * v1.y + v1.z * v1.z + v1.w * v1.w;
#pragma unroll
  for (int m = 1; m < 64; m <<= 1) { s += __shfl_xor(s, m); ss += __shfl_xor(ss, m); }
  const float mu  = s * (1.f / kH);
  const float var = ss * (1.f / kH) - mu * mu;
  const float rs  = 1.f / sqrtf(var + 1e-5f);
  const float4 g0 = *(const float4*)(g + lane * 8);
  const float4 g1 = *(const float4*)(g + lane * 8 + 4);
  const float4 b0 = *(const float4*)(bta + lane * 8);
  const float4 b1 = *(const float4*)(bta + lane * 8 + 4);
  float4 o0, o1;
  o0.x = (v0.x - mu) * rs * g0.x + b0.x;  o0.y = (v0.y - mu) * rs * g0.y + b0.y;
  o0.z = (v0.z - mu) * rs * g0.z + b0.z;  o0.w = (v0.w - mu) * rs * g0.w + b0.w;
  o1.x = (v1.x - mu) * rs * g1.x + b1.x;  o1.y = (v1.y - mu) * rs * g1.y + b1.y;
  o1.z = (v1.z - mu) * rs * g1.z + b1.z;  o1.w = (v1.w - mu) * rs * g1.w + b1.w;
  *(float4*)(xp + lane * 8)     = o0;
  *(float4*)(xp + lane * 8 + 4) = o1;
}

// ---------------- 1/(||k||^2 + eps): one wave per token, for ks and ke
__global__ __launch_bounds__(256) void invnorm_kernel(
    const float* __restrict__ ks, const float* __restrict__ ke,
    float* __restrict__ inv_s, float* __restrict__ inv_e, int tok0)
{
  const int wid  = threadIdx.x >> 6;
  const int lane = threadIdx.x & 63;
  const int tok  = tok0 + blockIdx.x * 4 + wid;
  const float4 a = *(const float4*)(ks + (size_t)tok * kHalf + lane * 4);
  const float4 b = *(const float4*)(ke + (size_t)tok * kHalf + lane * 4);
  float sa = a.x * a.x + a.y * a.y + a.z * a.z + a.w * a.w;
  float sb = b.x * b.x + b.y * b.y + b.z * b.z + b.w * b.w;
#pragma unroll
  for (int m = 1; m < 64; m <<= 1) { sa += __shfl_xor(sa, m); sb += __shfl_xor(sb, m); }
  if (lane == 0) {
    inv_s[tok] = 1.f / (sa + 1e-6f);
    inv_e[tok] = 1.f / (sb + 1e-6f);
  }
}

// ---------------- delta-rule scan: 2048 independent waves, no LDS, no barriers.
// Wave = (b, mat, slab): owns 16 rows x 256 cols of M in VGPRs.
// lane = rb*16 + jg: owns rows slab*16+rb*4+{0..3}, cols jg*16+{0..15}.
__global__ __launch_bounds__(256) void scan_kernel(
    const float* __restrict__ ks, const float* __restrict__ ke,
    const float* __restrict__ inv_s, const float* __restrict__ inv_e,
    const float* __restrict__ wts, float* __restrict__ c_out)
{
  const int wave = blockIdx.x * 4 + (threadIdx.x >> 6);
  const int lane = threadIdx.x & 63;
  const int b    = wave >> 5;
  const int sub  = wave & 31;
  const int mat  = sub >> 4;          // 0 = semantic, 1 = episodic
  const int slab = sub & 15;
  const int jg   = lane & 15;
  const int rb   = lane >> 4;
  const int row0 = slab * 16 + rb * 4;
  const int col0 = jg * 16;
  const float* kbase   = (mat ? ke : ks) + (size_t)b * ((size_t)kL * kHalf);
  const float* invbase = (mat ? inv_e : inv_s) + (size_t)b * kL;

  float M[4][16];
#pragma unroll
  for (int r = 0; r < 4; ++r)
#pragma unroll
    for (int c = 0; c < 16; ++c) M[r][c] = 0.f;

  float kc[16], kr[4], inv, wt;
  {
    const float* kp = kbase;
    const float4 c0 = *(const float4*)(kp + col0);
    const float4 c1 = *(const float4*)(kp + col0 + 4);
    const float4 c2 = *(const float4*)(kp + col0 + 8);
    const float4 c3 = *(const float4*)(kp + col0 + 12);
    const float4 rr = *(const float4*)(kp + row0);
    kc[0]=c0.x; kc[1]=c0.y; kc[2]=c0.z; kc[3]=c0.w;
    kc[4]=c1.x; kc[5]=c1.y; kc[6]=c1.z; kc[7]=c1.w;
    kc[8]=c2.x; kc[9]=c2.y; kc[10]=c2.z; kc[11]=c2.w;
    kc[12]=c3.x; kc[13]=c3.y; kc[14]=c3.z; kc[15]=c3.w;
    kr[0]=rr.x; kr[1]=rr.y; kr[2]=rr.z; kr[3]=rr.w;
    inv = invbase[0];
    wt  = mat ? wts[0] : 1.f;
  }

  for (int t = 0; t < kL - 1; ++t) {
    // prefetch step t+1 (t+1 == L-1 is the final query, consumed after loop)
    const float* kp = kbase + (size_t)(t + 1) * kHalf;
    const float4 n0 = *(const float4*)(kp + col0);
    const float4 n1 = *(const float4*)(kp + col0 + 4);
    const float4 n2 = *(const float4*)(kp + col0 + 8);
    const float4 n3 = *(const float4*)(kp + col0 + 12);
    const float4 nr = *(const float4*)(kp + row0);
    const float ninv = invbase[t + 1];
    const float nwt  = mat ? wts[t + 1] : 1.f;

    float p0 = 0.f, p1 = 0.f, p2 = 0.f, p3 = 0.f;
#pragma unroll
    for (int c = 0; c < 16; ++c) {
      p0 += M[0][c] * kc[c];
      p1 += M[1][c] * kc[c];
      p2 += M[2][c] * kc[c];
      p3 += M[3][c] * kc[c];
    }
#pragma unroll
    for (int m = 1; m <= 8; m <<= 1) {
      p0 += __shfl_xor(p0, m);
      p1 += __shfl_xor(p1, m);
      p2 += __shfl_xor(p2, m);
      p3 += __shfl_xor(p3, m);
    }
    const float s0 = wt * (kr[0] - p0 * inv);
    const float s1 = wt * (kr[1] - p1 * inv);
    const float s2 = wt * (kr[2] - p2 * inv);
    const float s3 = wt * (kr[3] - p3 * inv);
#pragma unroll
    for (int c = 0; c < 16; ++c) {
      M[0][c] += s0 * kc[c];
      M[1][c] += s1 * kc[c];
      M[2][c] += s2 * kc[c];
      M[3][c] += s3 * kc[c];
    }
    kc[0]=n0.x; kc[1]=n0.y; kc[2]=n0.z; kc[3]=n0.w;
    kc[4]=n1.x; kc[5]=n1.y; kc[6]=n1.z; kc[7]=n1.w;
    kc[8]=n2.x; kc[9]=n2.y; kc[10]=n2.z; kc[11]=n2.w;
    kc[12]=n3.x; kc[13]=n3.y; kc[14]=n3.z; kc[15]=n3.w;
    kr[0]=nr.x; kr[1]=nr.y; kr[2]=nr.z; kr[3]=nr.w;
    inv = ninv; wt = nwt;
  }

  // final read-out: c = M @ k_last   (k_last is in kc/kr now)
  float p0 = 0.f, p1 = 0.f, p2 = 0.f, p3 = 0.f;
#pragma unroll
  for (int c = 0; c < 16; ++c) {
    p0 += M[0][c] * kc[c];
    p1 += M[1][c] * kc[c];
    p2 += M[2][c] * kc[c];
    p3 += M[3][c] * kc[c];
  }
#pragma unroll
  for (int m = 1; m <= 8; m <<= 1) {
    p0 += __shfl_xor(p0, m);
    p1 += __shfl_xor(p1, m);
    p2 += __shfl_xor(p2, m);
    p3 += __shfl_xor(p3, m);
  }
  if (jg == 0) {
    float4 o; o.x = p0; o.y = p1; o.z = p2; o.w = p3;
    *(float4*)(c_out + (size_t)b * (2 * kHalf) + mat * kHalf + row0) = o;
  }
}

// ---------------- output GEMM: (64 x 512) @ (512 x 32000) + out_b -> fp32
__global__ __launch_bounds__(256) void out_gemm(
    const float* __restrict__ A, const float* __restrict__ Bm,
    const float* __restrict__ bias, float* __restrict__ C)
{
  __shared__ float As[16][64];
  __shared__ float Bs[16][128];
  const int tid = threadIdx.x;
  const int bn0 = blockIdx.x * 128;
  const int tm = tid >> 4, tn = tid & 15;
  float acc[4][8];
#pragma unroll
  for (int i = 0; i < 4; ++i)
#pragma unroll
    for (int j = 0; j < 8; ++j) acc[i][j] = 0.f;

  const int am  = tid & 63;
  const int ak  = (tid >> 6) * 4;                  // 0,4,8,12
  const int bkr = tid >> 5;
  const int bcg = (tid & 31) * 4;

  for (int k0 = 0; k0 < kH; k0 += 16) {
    const float4 a0 = *(const float4*)(A + (size_t)am * kH + k0 + ak);
    const float4 b0 = *(const float4*)(Bm + (size_t)(k0 + bkr) * kV + bn0 + bcg);
    const float4 b1 = *(const float4*)(Bm + (size_t)(k0 + bkr + 8) * kV + bn0 + bcg);
    __syncthreads();
    As[ak + 0][am] = a0.x; As[ak + 1][am] = a0.y;
    As[ak + 2][am] = a0.z; As[ak + 3][am] = a0.w;
    *(float4*)&Bs[bkr][bcg]     = b0;
    *(float4*)&Bs[bkr + 8][bcg] = b1;
    __syncthreads();
#pragma unroll
    for (int kk = 0; kk < 16; ++kk) {
      const float4 aA = *(const float4*)&As[kk][tm * 4];
      const float4 bA = *(const float4*)&Bs[kk][tn * 4];
      const float4 bB = *(const float4*)&Bs[kk][64 + tn * 4];
      const float av[4] = {aA.x, aA.y, aA.z, aA.w};
      const float bv[8] = {bA.x, bA.y, bA.z, bA.w, bB.x, bB.y, bB.z, bB.w};
#pragma unroll
      for (int i = 0; i < 4; ++i)
#pragma unroll
        for (int j = 0; j < 8; ++j) acc[i][j] += av[i] * bv[j];
    }
  }

#pragma unroll
  for (int i = 0; i < 4; ++i) {
    const int row = tm * 4 + i;
#pragma unroll
    for (int hh = 0; hh < 2; ++hh) {
      const int n0 = bn0 + tn * 4 + hh * 64;
      const float4 bb = *(const float4*)(bias + n0);
      float4 o;
      o.x = acc[i][hh * 4 + 0] + bb.x;
      o.y = acc[i][hh * 4 + 1] + bb.y;
      o.z = acc[i][hh * 4 + 2] + bb.z;
      o.w = acc[i][hh * 4 + 3] + bb.w;
      *(float4*)(C + (size_t)row * kV + n0) = o;
    }
  }
}

}  // namespace

extern "C" void kernel_launch(void* const* d_in, const int* in_sizes, int n_in,
                              void* d_out, int out_size, void* d_ws, size_t ws_size,
                              hipStream_t stream)
{
  const int*   seq     = (const int*)  d_in[0];
  const float* embed   = (const float*)d_in[1];
  const float* w1      = (const float*)d_in[2];
  const float* b1      = (const float*)d_in[3];
  const float* w2      = (const float*)d_in[4];
  const float* b2      = (const float*)d_in[5];
  const float* ln_g    = (const float*)d_in[6];
  const float* ln_b    = (const float*)d_in[7];
  const float* sem_w   = (const float*)d_in[8];
  const float* sem_b   = (const float*)d_in[9];
  const float* epi_w   = (const float*)d_in[10];
  const float* epi_b   = (const float*)d_in[11];
  const float* out_w   = (const float*)d_in[12];
  const float* out_b   = (const float*)d_in[13];
  const float* pos_emb = (const float*)d_in[14];
  const float* pos_w   = (const float*)d_in[15];
  const float* pos_b   = (const float*)d_in[16];
  float* out = (float*)d_out;   // reference output dtype is float32

  // workspace layout (floats): ~225 MB total
  float* ws    = (float*)d_ws;
  float* e_c   = ws;                                   // kChunk*512   (in-place e -> x -> h)
  float* t1_c  = e_c   + (size_t)kChunk * kH;          // kChunk*1024
  float* ks    = t1_c  + (size_t)kChunk * (2 * kH);    // 65536*256
  float* ke    = ks    + (size_t)kTok * kHalf;         // 65536*256
  float* inv_s = ke    + (size_t)kTok * kHalf;         // 65536
  float* inv_e = inv_s + kTok;                         // 65536
  float* wts   = inv_e + kTok;                         // 1024
  float* c_out = wts   + kL;                           // 64*512 (cs | ce)

  pos_kernel<<<dim3((kL + 255) / 256), dim3(256), 0, stream>>>(pos_emb, pos_w, pos_b, wts);

  for (int c = 0; c < kTok / kChunk; ++c) {
    const int tok0 = c * kChunk;
    gather_embed<<<dim3(kChunk / 4), dim3(256), 0, stream>>>(seq, embed, e_c, tok0);
    // t1 = relu(e @ w1 + b1)
    gemm128<true, false><<<dim3((2 * kH) / 128, kChunk / 128), dim3(256), 0, stream>>>(
        e_c, w1, b1, nullptr, t1_c, kChunk, 2 * kH, kH);
    // x = e + t1 @ w2 + b2   (in-place into e_c)
    gemm128<false, true><<<dim3(kH / 128, kChunk / 128), dim3(256), 0, stream>>>(
        t1_c, w2, b2, e_c, e_c, kChunk, kH, 2 * kH);
    ln_kernel<<<dim3(kChunk / 4), dim3(256), 0, stream>>>(e_c, ln_g, ln_b);
    // ks = h @ sem_w + sem_b ; ke = h @ epi_w + epi_b
    gemm128<false, false><<<dim3(kHalf / 128, kChunk / 128), dim3(256), 0, stream>>>(
        e_c, sem_w, sem_b, nullptr, ks + (size_t)tok0 * kHalf, kChunk, kHalf, kH);
    gemm128<false, false><<<dim3(kHalf / 128, kChunk / 128), dim3(256), 0, stream>>>(
        e_c, epi_w, epi_b, nullptr, ke + (size_t)tok0 * kHalf, kChunk, kHalf, kH);
    invnorm_kernel<<<dim3(kChunk / 4), dim3(256), 0, stream>>>(ks, ke, inv_s, inv_e, tok0);
  }

  scan_kernel<<<dim3(512), dim3(256), 0, stream>>>(ks, ke, inv_s, inv_e, wts, c_out);
  out_gemm<<<dim3(kV / 128), dim3(256), 0, stream>>>(c_out, out_w, out_b, out);

  (void)in_sizes; (void)n_in; (void)out_size; (void)ws_size;
}

// Round 4
// 2289.731 us; speedup vs baseline: 1.4409x; 1.4409x over previous
//
#include <hip/hip_runtime.h>
#include <hip/hip_bf16.h>
#include <math.h>

namespace {

constexpr int kH     = 512;
constexpr int kL     = 1024;
constexpr int kB     = 64;
constexpr int kHalf  = 256;
constexpr int kV     = 32000;
constexpr int kTok   = kB * kL;     // 65536
constexpr int kChunk = 8192;        // tokens per FFN chunk (8 chunks) — ws fits in 207 MB

using f32x4 = __attribute__((ext_vector_type(4))) float;
using f16x8 = __attribute__((ext_vector_type(8))) _Float16;

// ---------------- positional weights
__global__ void pos_kernel(const float* __restrict__ pos_emb,
                           const float* __restrict__ pos_w,
                           const float* __restrict__ pos_b,
                           float* __restrict__ wts)
{
  int t = blockIdx.x * blockDim.x + threadIdx.x;
  if (t >= kL) return;
  float z = pos_b[0];
#pragma unroll
  for (int p = 0; p < 16; ++p) z += pos_emb[t * 16 + p] * pos_w[p];
  wts[t] = 1.f / (1.f + expf(-z));
}

// ---------------- transpose + hi/lo fp16 split: W[K][N] fp32 -> Th/Tl[N][K]
__global__ __launch_bounds__(256) void transpose_split(
    const float* __restrict__ W, _Float16* __restrict__ Th,
    _Float16* __restrict__ Tl, int N, int kshift)
{
  const int idx = blockIdx.x * 256 + threadIdx.x;
  const int K = 1 << kshift;
  const int k = idx & (K - 1);
  const int n = idx >> kshift;
  const float w = W[(size_t)k * N + n];
  const _Float16 h = (_Float16)w;
  Th[idx] = h;
  Tl[idx] = (_Float16)(w - (float)h);
}

// ---------------- embedding gather -> hi/lo fp16. one wave per token
__global__ __launch_bounds__(256) void gather_split(
    const int* __restrict__ seq, const float* __restrict__ embed,
    _Float16* __restrict__ eh, _Float16* __restrict__ el, int tok0)
{
  const int wid  = threadIdx.x >> 6;
  const int lane = threadIdx.x & 63;
  const int ltok = blockIdx.x * 4 + wid;
  const int id   = seq[tok0 + ltok];
  const float* src = embed + (size_t)id * kH + lane * 8;
  const float4 v0 = *(const float4*)src;
  const float4 v1 = *(const float4*)(src + 4);
  const float vv[8] = {v0.x, v0.y, v0.z, v0.w, v1.x, v1.y, v1.z, v1.w};
  union { _Float16 h[8]; uint4 u; } ph, pl;
#pragma unroll
  for (int i = 0; i < 8; ++i) {
    ph.h[i] = (_Float16)vv[i];
    pl.h[i] = (_Float16)(vv[i] - (float)ph.h[i]);
  }
  *(uint4*)(eh + (size_t)ltok * kH + lane * 8) = ph.u;
  *(uint4*)(el + (size_t)ltok * kH + lane * 8) = pl.u;
}

// ---------------- split-fp16 MFMA GEMM: C[M,N] = (Ah+Al)[M,K] @ (Bh+Bl)[N,K]^T
// 128x128 tile, BK=32, 4 waves (2x2 of 64x64), 16x16x32 f16 MFMA, 3 products.
// EPI 0: relu(acc+bias) -> hi/lo fp16 (Oh/Ol, ld N)
// EPI 1: acc+bias+(Rh+Rl) -> fp32 Xout (ld N)
// EPI 2: acc + (n<256 ? bias : bias2) -> ks/ke fp32 (ld 256)
template <int EPI>
__global__ __launch_bounds__(256) void hgemm(
    const _Float16* __restrict__ Ah, const _Float16* __restrict__ Al,
    const _Float16* __restrict__ Bh, const _Float16* __restrict__ Bl,
    const float* __restrict__ bias, const float* __restrict__ bias2,
    const _Float16* __restrict__ Rh, const _Float16* __restrict__ Rl,
    float* __restrict__ Xout, _Float16* __restrict__ Oh, _Float16* __restrict__ Ol,
    float* __restrict__ ks, float* __restrict__ ke,
    int K, int N)
{
  __shared__ _Float16 lds[4][128][40];   // Ah, Al, Bh, Bl; +8 pad (80B stride)
  const int tid  = threadIdx.x;
  const int lane = tid & 63;
  const int wv   = tid >> 6;
  const int wm   = (wv >> 1) * 64;
  const int wn   = (wv & 1) * 64;
  const int bm0  = blockIdx.y * 128;
  const int bn0  = blockIdx.x * 128;

  f32x4 acc[4][4];
#pragma unroll
  for (int i = 0; i < 4; ++i)
#pragma unroll
    for (int j = 0; j < 4; ++j) acc[i][j] = {0.f, 0.f, 0.f, 0.f};

  const int sr = tid >> 1;            // staging row 0..127
  const int sc = (tid & 1) << 4;      // 0 or 16 (halves)
  const _Float16* gAh = Ah + (size_t)(bm0 + sr) * K + sc;
  const _Float16* gAl = Al + (size_t)(bm0 + sr) * K + sc;
  const _Float16* gBh = Bh + (size_t)(bn0 + sr) * K + sc;
  const _Float16* gBl = Bl + (size_t)(bn0 + sr) * K + sc;

  const int lrow = lane & 15;
  const int lk   = (lane >> 4) * 8;

  for (int k0 = 0; k0 < K; k0 += 32) {
    const uint4 vA0 = *(const uint4*)(gAh + k0);
    const uint4 vA1 = *(const uint4*)(gAh + k0 + 8);
    const uint4 vB0 = *(const uint4*)(gAl + k0);
    const uint4 vB1 = *(const uint4*)(gAl + k0 + 8);
    const uint4 vC0 = *(const uint4*)(gBh + k0);
    const uint4 vC1 = *(const uint4*)(gBh + k0 + 8);
    const uint4 vD0 = *(const uint4*)(gBl + k0);
    const uint4 vD1 = *(const uint4*)(gBl + k0 + 8);
    __syncthreads();
    *(uint4*)&lds[0][sr][sc]     = vA0;
    *(uint4*)&lds[0][sr][sc + 8] = vA1;
    *(uint4*)&lds[1][sr][sc]     = vB0;
    *(uint4*)&lds[1][sr][sc + 8] = vB1;
    *(uint4*)&lds[2][sr][sc]     = vC0;
    *(uint4*)&lds[2][sr][sc + 8] = vC1;
    *(uint4*)&lds[3][sr][sc]     = vD0;
    *(uint4*)&lds[3][sr][sc + 8] = vD1;
    __syncthreads();

    f16x8 fBh[4], fBl[4];
#pragma unroll
    for (int ni = 0; ni < 4; ++ni) {
      fBh[ni] = *(const f16x8*)&lds[2][wn + ni * 16 + lrow][lk];
      fBl[ni] = *(const f16x8*)&lds[3][wn + ni * 16 + lrow][lk];
    }
#pragma unroll
    for (int mi = 0; mi < 4; ++mi) {
      const f16x8 ah = *(const f16x8*)&lds[0][wm + mi * 16 + lrow][lk];
      const f16x8 al = *(const f16x8*)&lds[1][wm + mi * 16 + lrow][lk];
#pragma unroll
      for (int ni = 0; ni < 4; ++ni) {
        acc[mi][ni] = __builtin_amdgcn_mfma_f32_16x16x32_f16(ah, fBh[ni], acc[mi][ni], 0, 0, 0);
        acc[mi][ni] = __builtin_amdgcn_mfma_f32_16x16x32_f16(ah, fBl[ni], acc[mi][ni], 0, 0, 0);
        acc[mi][ni] = __builtin_amdgcn_mfma_f32_16x16x32_f16(al, fBh[ni], acc[mi][ni], 0, 0, 0);
      }
    }
  }

  // epilogue: D col = lane&15, row = (lane>>4)*4 + reg
  const int erow0 = (lane >> 4) * 4;
#pragma unroll
  for (int mi = 0; mi < 4; ++mi) {
#pragma unroll
    for (int ni = 0; ni < 4; ++ni) {
      const int gn = bn0 + wn + ni * 16 + (lane & 15);
      float bv;
      if (EPI == 2) bv = (gn < 256) ? bias[gn] : bias2[gn - 256];
      else          bv = bias[gn];
#pragma unroll
      for (int r = 0; r < 4; ++r) {
        const int gm = bm0 + wm + mi * 16 + erow0 + r;
        float v = acc[mi][ni][r] + bv;
        if (EPI == 0) {
          v = fmaxf(v, 0.f);
          const _Float16 h = (_Float16)v;
          Oh[(size_t)gm * N + gn] = h;
          Ol[(size_t)gm * N + gn] = (_Float16)(v - (float)h);
        } else if (EPI == 1) {
          v += (float)Rh[(size_t)gm * N + gn] + (float)Rl[(size_t)gm * N + gn];
          Xout[(size_t)gm * N + gn] = v;
        } else {
          if (gn < 256) ks[(size_t)gm * 256 + gn] = v;
          else          ke[(size_t)gm * 256 + (gn - 256)] = v;
        }
      }
    }
  }
}

// ---------------- LayerNorm: x fp32 -> hi/lo fp16. one wave per token
__global__ __launch_bounds__(256) void ln_split(
    const float* __restrict__ x, const float* __restrict__ g,
    const float* __restrict__ bta, _Float16* __restrict__ hh,
    _Float16* __restrict__ hl)
{
  const int wid  = threadIdx.x >> 6;
  const int lane = threadIdx.x & 63;
  const int ltok = blockIdx.x * 4 + wid;
  const float* xp = x + (size_t)ltok * kH;
  const float4 v0 = *(const float4*)(xp + lane * 8);
  const float4 v1 = *(const float4*)(xp + lane * 8 + 4);
  float s  = v0.x + v0.y + v0.z + v0.w + v1.x + v1.y + v1.z + v1.w;
  float ss = v0.x * v0.x + v0.y * v0.y + v0.z * v0.z + v0.w * v0.w +
             v1.x * v1.x + v1.y * v1.y + v1.z * v1.z + v1.w * v1.w;
#pragma unroll
  for (int m = 1; m < 64; m <<= 1) { s += __shfl_xor(s, m); ss += __shfl_xor(ss, m); }
  const float mu  = s * (1.f / kH);
  const float var = ss * (1.f / kH) - mu * mu;
  const float rs  = 1.f / sqrtf(var + 1e-5f);
  const float4 g0 = *(const float4*)(g + lane * 8);
  const float4 g1 = *(const float4*)(g + lane * 8 + 4);
  const float4 b0 = *(const float4*)(bta + lane * 8);
  const float4 b1 = *(const float4*)(bta + lane * 8 + 4);
  const float vv[8] = {v0.x, v0.y, v0.z, v0.w, v1.x, v1.y, v1.z, v1.w};
  const float gg[8] = {g0.x, g0.y, g0.z, g0.w, g1.x, g1.y, g1.z, g1.w};
  const float bb[8] = {b0.x, b0.y, b0.z, b0.w, b1.x, b1.y, b1.z, b1.w};
  union { _Float16 h[8]; uint4 u; } ph, pl;
#pragma unroll
  for (int i = 0; i < 8; ++i) {
    const float o = (vv[i] - mu) * rs * gg[i] + bb[i];
    ph.h[i] = (_Float16)o;
    pl.h[i] = (_Float16)(o - (float)ph.h[i]);
  }
  *(uint4*)(hh + (size_t)ltok * kH + lane * 8) = ph.u;
  *(uint4*)(hl + (size_t)ltok * kH + lane * 8) = pl.u;
}

// ---------------- 1/(||k||^2 + eps)
__global__ __launch_bounds__(256) void invnorm_kernel(
    const float* __restrict__ ks, const float* __restrict__ ke,
    float* __restrict__ inv_s, float* __restrict__ inv_e, int tok0)
{
  const int wid  = threadIdx.x >> 6;
  const int lane = threadIdx.x & 63;
  const int tok  = tok0 + blockIdx.x * 4 + wid;
  const float4 a = *(const float4*)(ks + (size_t)tok * kHalf + lane * 4);
  const float4 b = *(const float4*)(ke + (size_t)tok * kHalf + lane * 4);
  float sa = a.x * a.x + a.y * a.y + a.z * a.z + a.w * a.w;
  float sb = b.x * b.x + b.y * b.y + b.z * b.z + b.w * b.w;
#pragma unroll
  for (int m = 1; m < 64; m <<= 1) { sa += __shfl_xor(sa, m); sb += __shfl_xor(sb, m); }
  if (lane == 0) {
    inv_s[tok] = 1.f / (sa + 1e-6f);
    inv_e[tok] = 1.f / (sb + 1e-6f);
  }
}

// ---------------- delta-rule scan: 4096 independent waves (8 rows x 256 cols each)
// lane = rb*16 + jg: rows slab*8+rb*2+{0,1}, cols jg*16+{0..15}.
__global__ __launch_bounds__(256) void scan_kernel(
    const float* __restrict__ ks, const float* __restrict__ ke,
    const float* __restrict__ inv_s, const float* __restrict__ inv_e,
    const float* __restrict__ wts, float* __restrict__ c_out)
{
  const int wave = blockIdx.x * 4 + (threadIdx.x >> 6);
  const int lane = threadIdx.x & 63;
  const int b    = wave >> 6;
  const int sub  = wave & 63;
  const int mat  = sub >> 5;          // 0 = semantic, 1 = episodic
  const int slab = sub & 31;
  const int jg   = lane & 15;
  const int rb   = lane >> 4;
  const int row0 = slab * 8 + rb * 2;
  const int col0 = jg * 16;
  const float* kbase   = (mat ? ke : ks) + (size_t)b * ((size_t)kL * kHalf);
  const float* invbase = (mat ? inv_e : inv_s) + (size_t)b * kL;

  float M0[16], M1[16];
#pragma unroll
  for (int c = 0; c < 16; ++c) { M0[c] = 0.f; M1[c] = 0.f; }

  float kc[16], kr0, kr1, inv, wt;
  {
    const float* kp = kbase;
    const float4 c0 = *(const float4*)(kp + col0);
    const float4 c1 = *(const float4*)(kp + col0 + 4);
    const float4 c2 = *(const float4*)(kp + col0 + 8);
    const float4 c3 = *(const float4*)(kp + col0 + 12);
    const float2 rr = *(const float2*)(kp + row0);
    kc[0]=c0.x; kc[1]=c0.y; kc[2]=c0.z; kc[3]=c0.w;
    kc[4]=c1.x; kc[5]=c1.y; kc[6]=c1.z; kc[7]=c1.w;
    kc[8]=c2.x; kc[9]=c2.y; kc[10]=c2.z; kc[11]=c2.w;
    kc[12]=c3.x; kc[13]=c3.y; kc[14]=c3.z; kc[15]=c3.w;
    kr0 = rr.x; kr1 = rr.y;
    inv = invbase[0];
    wt  = mat ? wts[0] : 1.f;
  }

  for (int t = 0; t < kL - 1; ++t) {
    const float* kp = kbase + (size_t)(t + 1) * kHalf;
    const float4 n0 = *(const float4*)(kp + col0);
    const float4 n1 = *(const float4*)(kp + col0 + 4);
    const float4 n2 = *(const float4*)(kp + col0 + 8);
    const float4 n3 = *(const float4*)(kp + col0 + 12);
    const float2 nr = *(const float2*)(kp + row0);
    const float ninv = invbase[t + 1];
    const float nwt  = mat ? wts[t + 1] : 1.f;

    float p0a = 0.f, p0b = 0.f, p1a = 0.f, p1b = 0.f;
#pragma unroll
    for (int c = 0; c < 8; ++c) {
      p0a += M0[c] * kc[c];
      p1a += M1[c] * kc[c];
    }
#pragma unroll
    for (int c = 8; c < 16; ++c) {
      p0b += M0[c] * kc[c];
      p1b += M1[c] * kc[c];
    }
    float p0 = p0a + p0b, p1 = p1a + p1b;
#pragma unroll
    for (int m = 1; m <= 8; m <<= 1) {
      p0 += __shfl_xor(p0, m);
      p1 += __shfl_xor(p1, m);
    }
    const float s0 = wt * (kr0 - p0 * inv);
    const float s1 = wt * (kr1 - p1 * inv);
#pragma unroll
    for (int c = 0; c < 16; ++c) {
      M0[c] += s0 * kc[c];
      M1[c] += s1 * kc[c];
    }
    kc[0]=n0.x; kc[1]=n0.y; kc[2]=n0.z; kc[3]=n0.w;
    kc[4]=n1.x; kc[5]=n1.y; kc[6]=n1.z; kc[7]=n1.w;
    kc[8]=n2.x; kc[9]=n2.y; kc[10]=n2.z; kc[11]=n2.w;
    kc[12]=n3.x; kc[13]=n3.y; kc[14]=n3.z; kc[15]=n3.w;
    kr0 = nr.x; kr1 = nr.y;
    inv = ninv; wt = nwt;
  }

  float p0a = 0.f, p0b = 0.f, p1a = 0.f, p1b = 0.f;
#pragma unroll
  for (int c = 0; c < 8; ++c) { p0a += M0[c] * kc[c]; p1a += M1[c] * kc[c]; }
#pragma unroll
  for (int c = 8; c < 16; ++c) { p0b += M0[c] * kc[c]; p1b += M1[c] * kc[c]; }
  float p0 = p0a + p0b, p1 = p1a + p1b;
#pragma unroll
  for (int m = 1; m <= 8; m <<= 1) {
    p0 += __shfl_xor(p0, m);
    p1 += __shfl_xor(p1, m);
  }
  if (jg == 0) {
    float2 o; o.x = p0; o.y = p1;
    *(float2*)(c_out + (size_t)b * (2 * kHalf) + mat * kHalf + row0) = o;
  }
}

// ---------------- output GEMM: (64 x 512) @ (512 x 32000) + out_b -> fp32
__global__ __launch_bounds__(256) void out_gemm(
    const float* __restrict__ A, const float* __restrict__ Bm,
    const float* __restrict__ bias, float* __restrict__ C)
{
  __shared__ float As[16][64];
  __shared__ float Bs[16][128];
  const int tid = threadIdx.x;
  const int bn0 = blockIdx.x * 128;
  const int tm = tid >> 4, tn = tid & 15;
  float acc[4][8];
#pragma unroll
  for (int i = 0; i < 4; ++i)
#pragma unroll
    for (int j = 0; j < 8; ++j) acc[i][j] = 0.f;

  const int am  = tid & 63;
  const int ak  = (tid >> 6) * 4;
  const int bkr = tid >> 5;
  const int bcg = (tid & 31) * 4;

  for (int k0 = 0; k0 < kH; k0 += 16) {
    const float4 a0 = *(const float4*)(A + (size_t)am * kH + k0 + ak);
    const float4 b0 = *(const float4*)(Bm + (size_t)(k0 + bkr) * kV + bn0 + bcg);
    const float4 b1 = *(const float4*)(Bm + (size_t)(k0 + bkr + 8) * kV + bn0 + bcg);
    __syncthreads();
    As[ak + 0][am] = a0.x; As[ak + 1][am] = a0.y;
    As[ak + 2][am] = a0.z; As[ak + 3][am] = a0.w;
    *(float4*)&Bs[bkr][bcg]     = b0;
    *(float4*)&Bs[bkr + 8][bcg] = b1;
    __syncthreads();
#pragma unroll
    for (int kk = 0; kk < 16; ++kk) {
      const float4 aA = *(const float4*)&As[kk][tm * 4];
      const float4 bA = *(const float4*)&Bs[kk][tn * 4];
      const float4 bB = *(const float4*)&Bs[kk][64 + tn * 4];
      const float av[4] = {aA.x, aA.y, aA.z, aA.w};
      const float bv[8] = {bA.x, bA.y, bA.z, bA.w, bB.x, bB.y, bB.z, bB.w};
#pragma unroll
      for (int i = 0; i < 4; ++i)
#pragma unroll
        for (int j = 0; j < 8; ++j) acc[i][j] += av[i] * bv[j];
    }
  }

#pragma unroll
  for (int i = 0; i < 4; ++i) {
    const int row = tm * 4 + i;
#pragma unroll
    for (int hh = 0; hh < 2; ++hh) {
      const int n0 = bn0 + tn * 4 + hh * 64;
      const float4 bb = *(const float4*)(bias + n0);
      float4 o;
      o.x = acc[i][hh * 4 + 0] + bb.x;
      o.y = acc[i][hh * 4 + 1] + bb.y;
      o.z = acc[i][hh * 4 + 2] + bb.z;
      o.w = acc[i][hh * 4 + 3] + bb.w;
      *(float4*)(C + (size_t)row * kV + n0) = o;
    }
  }
}

}  // namespace

extern "C" void kernel_launch(void* const* d_in, const int* in_sizes, int n_in,
                              void* d_out, int out_size, void* d_ws, size_t ws_size,
                              hipStream_t stream)
{
  const int*   seq     = (const int*)  d_in[0];
  const float* embed   = (const float*)d_in[1];
  const float* w1      = (const float*)d_in[2];
  const float* b1      = (const float*)d_in[3];
  const float* w2      = (const float*)d_in[4];
  const float* b2      = (const float*)d_in[5];
  const float* ln_g    = (const float*)d_in[6];
  const float* ln_b    = (const float*)d_in[7];
  const float* sem_w   = (const float*)d_in[8];
  const float* sem_b   = (const float*)d_in[9];
  const float* epi_w   = (const float*)d_in[10];
  const float* epi_b   = (const float*)d_in[11];
  const float* out_w   = (const float*)d_in[12];
  const float* out_b   = (const float*)d_in[13];
  const float* pos_emb = (const float*)d_in[14];
  const float* pos_w   = (const float*)d_in[15];
  const float* pos_b   = (const float*)d_in[16];
  float* out = (float*)d_out;

  // ---- workspace layout: 207.2 MB total (< 235.6 MB known-good from round 2)
  char* p = (char*)d_ws;
  _Float16* w1th = (_Float16*)p; p += (size_t)1024 * 512 * 2;
  _Float16* w1tl = (_Float16*)p; p += (size_t)1024 * 512 * 2;
  _Float16* w2th = (_Float16*)p; p += (size_t)512 * 1024 * 2;
  _Float16* w2tl = (_Float16*)p; p += (size_t)512 * 1024 * 2;
  _Float16* wseh = (_Float16*)p; p += (size_t)512 * 512 * 2;
  _Float16* wsel = (_Float16*)p; p += (size_t)512 * 512 * 2;
  _Float16* eh   = (_Float16*)p; p += (size_t)kChunk * kH * 2;
  _Float16* el   = (_Float16*)p; p += (size_t)kChunk * kH * 2;
  _Float16* t1h  = (_Float16*)p; p += (size_t)kChunk * 1024 * 2;
  _Float16* t1l  = (_Float16*)p; p += (size_t)kChunk * 1024 * 2;
  float*    x    = (float*)p;    p += (size_t)kChunk * kH * 4;
  float*    ks   = (float*)p;    p += (size_t)kTok * kHalf * 4;
  float*    ke   = (float*)p;    p += (size_t)kTok * kHalf * 4;
  float*    invs = (float*)p;    p += (size_t)kTok * 4;
  float*    inve = (float*)p;    p += (size_t)kTok * 4;
  float*    wts  = (float*)p;    p += (size_t)kL * 4;
  float*    cout_= (float*)p;    p += (size_t)kB * 512 * 4;
  _Float16* hh   = t1h;          // alias: t1 dead once x is written
  _Float16* hl   = t1l;

  pos_kernel<<<dim3((kL + 255) / 256), dim3(256), 0, stream>>>(pos_emb, pos_w, pos_b, wts);
  transpose_split<<<dim3(1024 * 512 / 256), dim3(256), 0, stream>>>(w1, w1th, w1tl, 1024, 9);
  transpose_split<<<dim3(512 * 1024 / 256), dim3(256), 0, stream>>>(w2, w2th, w2tl, 512, 10);
  transpose_split<<<dim3(256 * 512 / 256), dim3(256), 0, stream>>>(sem_w, wseh, wsel, 256, 9);
  transpose_split<<<dim3(256 * 512 / 256), dim3(256), 0, stream>>>(
      epi_w, wseh + (size_t)256 * 512, wsel + (size_t)256 * 512, 256, 9);

  for (int c = 0; c < kTok / kChunk; ++c) {
    const int tok0 = c * kChunk;
    gather_split<<<dim3(kChunk / 4), dim3(256), 0, stream>>>(seq, embed, eh, el, tok0);
    // t1 = relu(e @ w1 + b1)          [kChunk x 1024]
    hgemm<0><<<dim3(1024 / 128, kChunk / 128), dim3(256), 0, stream>>>(
        eh, el, w1th, w1tl, b1, nullptr, nullptr, nullptr,
        nullptr, t1h, t1l, nullptr, nullptr, 512, 1024);
    // x = e + t1 @ w2 + b2            [kChunk x 512]
    hgemm<1><<<dim3(512 / 128, kChunk / 128), dim3(256), 0, stream>>>(
        t1h, t1l, w2th, w2tl, b2, nullptr, eh, el,
        x, nullptr, nullptr, nullptr, nullptr, 1024, 512);
    ln_split<<<dim3(kChunk / 4), dim3(256), 0, stream>>>(x, ln_g, ln_b, hh, hl);
    // ks|ke = h @ [sem_w | epi_w] + b [kChunk x 512 -> 2 x 256]
    hgemm<2><<<dim3(512 / 128, kChunk / 128), dim3(256), 0, stream>>>(
        hh, hl, wseh, wsel, sem_b, epi_b, nullptr, nullptr,
        nullptr, nullptr, nullptr, ks + (size_t)tok0 * kHalf, ke + (size_t)tok0 * kHalf,
        512, 512);
    invnorm_kernel<<<dim3(kChunk / 4), dim3(256), 0, stream>>>(ks, ke, invs, inve, tok0);
  }

  scan_kernel<<<dim3(1024), dim3(256), 0, stream>>>(ks, ke, invs, inve, wts, cout_);
  out_gemm<<<dim3(kV / 128), dim3(256), 0, stream>>>(cout_, out_w, out_b, out);

  (void)in_sizes; (void)n_in; (void)out_size; (void)ws_size;
}

// Round 5
// 1866.454 us; speedup vs baseline: 1.7677x; 1.2268x over previous
//
#include <hip/hip_runtime.h>
#include <hip/hip_bf16.h>
#include <math.h>

namespace {

constexpr int kH     = 512;
constexpr int kL     = 1024;
constexpr int kB     = 64;
constexpr int kHalf  = 256;
constexpr int kV     = 32000;
constexpr int kTok   = kB * kL;     // 65536
constexpr int kChunk = 8192;        // tokens per FFN chunk (8 chunks)

using f32x4 = __attribute__((ext_vector_type(4))) float;
using f16x8 = __attribute__((ext_vector_type(8))) _Float16;

__device__ inline void fsplit(float v, _Float16& h, _Float16& l) {
  h = (_Float16)v;
  l = (_Float16)(v - (float)h);
}

// ---------------- positional weights
__global__ void pos_kernel(const float* __restrict__ pos_emb,
                           const float* __restrict__ pos_w,
                           const float* __restrict__ pos_b,
                           float* __restrict__ wts)
{
  int t = blockIdx.x * blockDim.x + threadIdx.x;
  if (t >= kL) return;
  float z = pos_b[0];
#pragma unroll
  for (int p = 0; p < 16; ++p) z += pos_emb[t * 16 + p] * pos_w[p];
  wts[t] = 1.f / (1.f + expf(-z));
}

// ---------------- transpose + hi/lo fp16 split: W[K][N] fp32 -> Th/Tl[N][K]
__global__ __launch_bounds__(256) void transpose_split(
    const float* __restrict__ W, _Float16* __restrict__ Th,
    _Float16* __restrict__ Tl, int N, int kshift)
{
  const int idx = blockIdx.x * 256 + threadIdx.x;
  const int K = 1 << kshift;
  const int k = idx & (K - 1);
  const int n = idx >> kshift;
  const float w = W[(size_t)k * N + n];
  const _Float16 h = (_Float16)w;
  Th[idx] = h;
  Tl[idx] = (_Float16)(w - (float)h);
}

// ---------------- embedding gather -> hi/lo fp16. one wave per token
__global__ __launch_bounds__(256) void gather_split(
    const int* __restrict__ seq, const float* __restrict__ embed,
    _Float16* __restrict__ eh, _Float16* __restrict__ el, int tok0)
{
  const int wid  = threadIdx.x >> 6;
  const int lane = threadIdx.x & 63;
  const int ltok = blockIdx.x * 4 + wid;
  const int id   = seq[tok0 + ltok];
  const float* src = embed + (size_t)id * kH + lane * 8;
  const float4 v0 = *(const float4*)src;
  const float4 v1 = *(const float4*)(src + 4);
  const float vv[8] = {v0.x, v0.y, v0.z, v0.w, v1.x, v1.y, v1.z, v1.w};
  union { _Float16 h[8]; uint4 u; } ph, pl;
#pragma unroll
  for (int i = 0; i < 8; ++i) fsplit(vv[i], ph.h[i], pl.h[i]);
  *(uint4*)(eh + (size_t)ltok * kH + lane * 8) = ph.u;
  *(uint4*)(el + (size_t)ltok * kH + lane * 8) = pl.u;
}

// ---------------- split-fp16 MFMA GEMM (unchanged from round 4, validated)
template <int EPI>
__global__ __launch_bounds__(256) void hgemm(
    const _Float16* __restrict__ Ah, const _Float16* __restrict__ Al,
    const _Float16* __restrict__ Bh, const _Float16* __restrict__ Bl,
    const float* __restrict__ bias, const float* __restrict__ bias2,
    const _Float16* __restrict__ Rh, const _Float16* __restrict__ Rl,
    float* __restrict__ Xout, _Float16* __restrict__ Oh, _Float16* __restrict__ Ol,
    float* __restrict__ ks, float* __restrict__ ke,
    int K, int N)
{
  __shared__ _Float16 lds[4][128][40];
  const int tid  = threadIdx.x;
  const int lane = tid & 63;
  const int wv   = tid >> 6;
  const int wm   = (wv >> 1) * 64;
  const int wn   = (wv & 1) * 64;
  const int bm0  = blockIdx.y * 128;
  const int bn0  = blockIdx.x * 128;

  f32x4 acc[4][4];
#pragma unroll
  for (int i = 0; i < 4; ++i)
#pragma unroll
    for (int j = 0; j < 4; ++j) acc[i][j] = {0.f, 0.f, 0.f, 0.f};

  const int sr = tid >> 1;
  const int sc = (tid & 1) << 4;
  const _Float16* gAh = Ah + (size_t)(bm0 + sr) * K + sc;
  const _Float16* gAl = Al + (size_t)(bm0 + sr) * K + sc;
  const _Float16* gBh = Bh + (size_t)(bn0 + sr) * K + sc;
  const _Float16* gBl = Bl + (size_t)(bn0 + sr) * K + sc;

  const int lrow = lane & 15;
  const int lk   = (lane >> 4) * 8;

  for (int k0 = 0; k0 < K; k0 += 32) {
    const uint4 vA0 = *(const uint4*)(gAh + k0);
    const uint4 vA1 = *(const uint4*)(gAh + k0 + 8);
    const uint4 vB0 = *(const uint4*)(gAl + k0);
    const uint4 vB1 = *(const uint4*)(gAl + k0 + 8);
    const uint4 vC0 = *(const uint4*)(gBh + k0);
    const uint4 vC1 = *(const uint4*)(gBh + k0 + 8);
    const uint4 vD0 = *(const uint4*)(gBl + k0);
    const uint4 vD1 = *(const uint4*)(gBl + k0 + 8);
    __syncthreads();
    *(uint4*)&lds[0][sr][sc]     = vA0;
    *(uint4*)&lds[0][sr][sc + 8] = vA1;
    *(uint4*)&lds[1][sr][sc]     = vB0;
    *(uint4*)&lds[1][sr][sc + 8] = vB1;
    *(uint4*)&lds[2][sr][sc]     = vC0;
    *(uint4*)&lds[2][sr][sc + 8] = vC1;
    *(uint4*)&lds[3][sr][sc]     = vD0;
    *(uint4*)&lds[3][sr][sc + 8] = vD1;
    __syncthreads();

    f16x8 fBh[4], fBl[4];
#pragma unroll
    for (int ni = 0; ni < 4; ++ni) {
      fBh[ni] = *(const f16x8*)&lds[2][wn + ni * 16 + lrow][lk];
      fBl[ni] = *(const f16x8*)&lds[3][wn + ni * 16 + lrow][lk];
    }
#pragma unroll
    for (int mi = 0; mi < 4; ++mi) {
      const f16x8 ah = *(const f16x8*)&lds[0][wm + mi * 16 + lrow][lk];
      const f16x8 al = *(const f16x8*)&lds[1][wm + mi * 16 + lrow][lk];
#pragma unroll
      for (int ni = 0; ni < 4; ++ni) {
        acc[mi][ni] = __builtin_amdgcn_mfma_f32_16x16x32_f16(ah, fBh[ni], acc[mi][ni], 0, 0, 0);
        acc[mi][ni] = __builtin_amdgcn_mfma_f32_16x16x32_f16(ah, fBl[ni], acc[mi][ni], 0, 0, 0);
        acc[mi][ni] = __builtin_amdgcn_mfma_f32_16x16x32_f16(al, fBh[ni], acc[mi][ni], 0, 0, 0);
      }
    }
  }

  const int erow0 = (lane >> 4) * 4;
#pragma unroll
  for (int mi = 0; mi < 4; ++mi) {
#pragma unroll
    for (int ni = 0; ni < 4; ++ni) {
      const int gn = bn0 + wn + ni * 16 + (lane & 15);
      float bv;
      if (EPI == 2) bv = (gn < 256) ? bias[gn] : bias2[gn - 256];
      else          bv = bias[gn];
#pragma unroll
      for (int r = 0; r < 4; ++r) {
        const int gm = bm0 + wm + mi * 16 + erow0 + r;
        float v = acc[mi][ni][r] + bv;
        if (EPI == 0) {
          v = fmaxf(v, 0.f);
          const _Float16 h = (_Float16)v;
          Oh[(size_t)gm * N + gn] = h;
          Ol[(size_t)gm * N + gn] = (_Float16)(v - (float)h);
        } else if (EPI == 1) {
          v += (float)Rh[(size_t)gm * N + gn] + (float)Rl[(size_t)gm * N + gn];
          Xout[(size_t)gm * N + gn] = v;
        } else {
          if (gn < 256) ks[(size_t)gm * 256 + gn] = v;
          else          ke[(size_t)gm * 256 + (gn - 256)] = v;
        }
      }
    }
  }
}

// ---------------- LayerNorm: x fp32 -> hi/lo fp16
__global__ __launch_bounds__(256) void ln_split(
    const float* __restrict__ x, const float* __restrict__ g,
    const float* __restrict__ bta, _Float16* __restrict__ hh,
    _Float16* __restrict__ hl)
{
  const int wid  = threadIdx.x >> 6;
  const int lane = threadIdx.x & 63;
  const int ltok = blockIdx.x * 4 + wid;
  const float* xp = x + (size_t)ltok * kH;
  const float4 v0 = *(const float4*)(xp + lane * 8);
  const float4 v1 = *(const float4*)(xp + lane * 8 + 4);
  float s  = v0.x + v0.y + v0.z + v0.w + v1.x + v1.y + v1.z + v1.w;
  float ss = v0.x * v0.x + v0.y * v0.y + v0.z * v0.z + v0.w * v0.w +
             v1.x * v1.x + v1.y * v1.y + v1.z * v1.z + v1.w * v1.w;
#pragma unroll
  for (int m = 1; m < 64; m <<= 1) { s += __shfl_xor(s, m); ss += __shfl_xor(ss, m); }
  const float mu  = s * (1.f / kH);
  const float var = ss * (1.f / kH) - mu * mu;
  const float rs  = 1.f / sqrtf(var + 1e-5f);
  const float4 g0 = *(const float4*)(g + lane * 8);
  const float4 g1 = *(const float4*)(g + lane * 8 + 4);
  const float4 b0 = *(const float4*)(bta + lane * 8);
  const float4 b1 = *(const float4*)(bta + lane * 8 + 4);
  const float vv[8] = {v0.x, v0.y, v0.z, v0.w, v1.x, v1.y, v1.z, v1.w};
  const float gg[8] = {g0.x, g0.y, g0.z, g0.w, g1.x, g1.y, g1.z, g1.w};
  const float bb[8] = {b0.x, b0.y, b0.z, b0.w, b1.x, b1.y, b1.z, b1.w};
  union { _Float16 h[8]; uint4 u; } ph, pl;
#pragma unroll
  for (int i = 0; i < 8; ++i) {
    const float o = (vv[i] - mu) * rs * gg[i] + bb[i];
    fsplit(o, ph.h[i], pl.h[i]);
  }
  *(uint4*)(hh + (size_t)ltok * kH + lane * 8) = ph.u;
  *(uint4*)(hl + (size_t)ltok * kH + lane * 8) = pl.u;
}

// ---------------- 1/(||k||^2 + eps)
__global__ __launch_bounds__(256) void invnorm_kernel(
    const float* __restrict__ ks, const float* __restrict__ ke,
    float* __restrict__ inv_s, float* __restrict__ inv_e, int tok0)
{
  const int wid  = threadIdx.x >> 6;
  const int lane = threadIdx.x & 63;
  const int tok  = tok0 + blockIdx.x * 4 + wid;
  const float4 a = *(const float4*)(ks + (size_t)tok * kHalf + lane * 4);
  const float4 b = *(const float4*)(ke + (size_t)tok * kHalf + lane * 4);
  float sa = a.x * a.x + a.y * a.y + a.z * a.z + a.w * a.w;
  float sb = b.x * b.x + b.y * b.y + b.z * b.z + b.w * b.w;
#pragma unroll
  for (int m = 1; m < 64; m <<= 1) { sa += __shfl_xor(sa, m); sb += __shfl_xor(sb, m); }
  if (lane == 0) {
    inv_s[tok] = 1.f / (sa + 1e-6f);
    inv_e[tok] = 1.f / (sb + 1e-6f);
  }
}

// ---------------- chunked WY delta-rule scan.
// S = M^T (256x256 fp32). Recurrence: S_t = S_{t-1} + k_t u_t^T,
//   u_t = w_t k_t - (w_t inv_t)(S_{t-1}^T k_t),
//   S_{t-1}^T k_t = S_0^T k_t + sum_{s<t} (k_s.k_t) u_s.
// WG = (b, mat, quarter): owns 64 cols of S (full 256 rows). 512 WGs, 2/CU.
// Per chunk (C=64): Q=K@S0, G=KK^T (split-f16 MFMA), fp32 barrier-free solve,
// S += K^T U (split-f16 MFMA, accumulates in fp32 regs).
struct PhaseA { _Float16 Kph[64][72], Kpl[64][72], Sph[64][72], Spl[64][72]; };
struct PhaseB { float Rr[64][68]; _Float16 Uh[64][72], Ul[64][72]; };
union ShU { PhaseA a; PhaseB b; };

__global__ __launch_bounds__(256, 2) void scan_chunked(
    const float* __restrict__ ks, const float* __restrict__ ke,
    const float* __restrict__ inv_s, const float* __restrict__ inv_e,
    const float* __restrict__ wts, float* __restrict__ c_out)
{
  __shared__ ShU sh;
  __shared__ float Gm[64][68];    // Gm[x][y] = k_x . k_y (symmetric, fully written)
  __shared__ float aS[64], wS[64];
  __shared__ float cred[4][64];

  const int tid  = threadIdx.x;
  const int lane = tid & 63;
  const int wv   = tid >> 6;
  const int l15  = lane & 15;
  const int quad = lane >> 4;
  const int wg   = blockIdx.x;
  const int b    = wg >> 3;
  const int mat  = (wg >> 2) & 1;
  const int j0   = (wg & 3) * 64;
  const float* kb  = (mat ? ke : ks) + (size_t)b * ((size_t)kL * kHalf);
  const float* ivb = (mat ? inv_e : inv_s) + (size_t)b * kL;

  // S tiles: mi (0..3) x nt (0..3); row = 64*wv + mi*16 + quad*4 + r, col = j0 + nt*16 + l15
  f32x4 S[16];
#pragma unroll
  for (int i = 0; i < 16; ++i) S[i] = {0.f, 0.f, 0.f, 0.f};

  for (int ck = 0; ck < 16; ++ck) {
    const int tok0 = ck * 64;
    if (tid < 64) {
      const float w  = mat ? wts[tok0 + tid] : 1.f;
      wS[tid] = w;
      aS[tid] = w * ivb[tok0 + tid];
    }
    f32x4 Qa[4], Ga[4];
#pragma unroll
    for (int i = 0; i < 4; ++i) { Qa[i] = {0.f,0.f,0.f,0.f}; Ga[i] = {0.f,0.f,0.f,0.f}; }

    for (int p = 0; p < 4; ++p) {
      __syncthreads();   // prior panel / prior-chunk Uh readers done (alias region)
      {  // stage K panel: K[t][64p..64p+63] -> hi/lo f16
        const int t = tid >> 2, dg = (tid & 3) * 16;
        const float* src = kb + (size_t)(tok0 + t) * kHalf + p * 64 + dg;
        const float4 v0 = *(const float4*)(src);
        const float4 v1 = *(const float4*)(src + 4);
        const float4 v2 = *(const float4*)(src + 8);
        const float4 v3 = *(const float4*)(src + 12);
        const float vv[16] = {v0.x,v0.y,v0.z,v0.w, v1.x,v1.y,v1.z,v1.w,
                              v2.x,v2.y,v2.z,v2.w, v3.x,v3.y,v3.z,v3.w};
        union { _Float16 h[16]; uint4 u[2]; } ph, pl;
#pragma unroll
        for (int i = 0; i < 16; ++i) fsplit(vv[i], ph.h[i], pl.h[i]);
        *(uint4*)&sh.a.Kph[t][dg]     = ph.u[0];
        *(uint4*)&sh.a.Kph[t][dg + 8] = ph.u[1];
        *(uint4*)&sh.a.Kpl[t][dg]     = pl.u[0];
        *(uint4*)&sh.a.Kpl[t][dg + 8] = pl.u[1];
      }
      if (wv == p) {  // stage S panel p (rows 64p..64p+63 owned by wave p): [col][row]
#pragma unroll
        for (int mi = 0; mi < 4; ++mi)
#pragma unroll
          for (int nt = 0; nt < 4; ++nt) {
            const f32x4 v = S[mi * 4 + nt];
            union { _Float16 h[4]; uint2 u; } qh, ql;
#pragma unroll
            for (int r = 0; r < 4; ++r) fsplit(v[r], qh.h[r], ql.h[r]);
            *(uint2*)&sh.a.Sph[nt * 16 + l15][mi * 16 + quad * 4] = qh.u;
            *(uint2*)&sh.a.Spl[nt * 16 + l15][mi * 16 + quad * 4] = ql.u;
          }
      }
      __syncthreads();
      // MFMAs: Q (m-tile = wv over t, n over cols), G (m-tile = wv, n over t)
#pragma unroll
      for (int kit = 0; kit < 2; ++kit) {
        const int ko = kit * 32 + quad * 8;
        const f16x8 ah = *(const f16x8*)&sh.a.Kph[wv * 16 + l15][ko];
        const f16x8 al = *(const f16x8*)&sh.a.Kpl[wv * 16 + l15][ko];
#pragma unroll
        for (int nt = 0; nt < 4; ++nt) {
          const f16x8 bh = *(const f16x8*)&sh.a.Sph[nt * 16 + l15][ko];
          const f16x8 bl = *(const f16x8*)&sh.a.Spl[nt * 16 + l15][ko];
          Qa[nt] = __builtin_amdgcn_mfma_f32_16x16x32_f16(ah, bh, Qa[nt], 0, 0, 0);
          Qa[nt] = __builtin_amdgcn_mfma_f32_16x16x32_f16(ah, bl, Qa[nt], 0, 0, 0);
          Qa[nt] = __builtin_amdgcn_mfma_f32_16x16x32_f16(al, bh, Qa[nt], 0, 0, 0);
        }
#pragma unroll
        for (int nt = 0; nt < 4; ++nt) {
          const f16x8 bh = *(const f16x8*)&sh.a.Kph[nt * 16 + l15][ko];
          const f16x8 bl = *(const f16x8*)&sh.a.Kpl[nt * 16 + l15][ko];
          Ga[nt] = __builtin_amdgcn_mfma_f32_16x16x32_f16(ah, bh, Ga[nt], 0, 0, 0);
          Ga[nt] = __builtin_amdgcn_mfma_f32_16x16x32_f16(ah, bl, Ga[nt], 0, 0, 0);
          Ga[nt] = __builtin_amdgcn_mfma_f32_16x16x32_f16(al, bh, Ga[nt], 0, 0, 0);
        }
      }
    }
    __syncthreads();   // all panel LDS reads done -> safe to write aliased Rr

    // Q -> Rr[t][col] ; G -> Gm[tn][tm..tm+3] (symmetric)
#pragma unroll
    for (int nt = 0; nt < 4; ++nt) {
#pragma unroll
      for (int r = 0; r < 4; ++r)
        sh.b.Rr[wv * 16 + quad * 4 + r][nt * 16 + l15] = Qa[nt][r];
      *(float4*)&Gm[nt * 16 + l15][wv * 16 + quad * 4] = *(const float4*)&Ga[nt];
    }
    // prefetch S-update A-fragments: K^T[row][t] from global (exact fp32 -> hi/lo)
    f16x8 uah[8], ual[8];
#pragma unroll
    for (int mi = 0; mi < 4; ++mi)
#pragma unroll
      for (int kit = 0; kit < 2; ++kit) {
        union { _Float16 h[8]; f16x8 v; } Ph, Pl;
        const int drow = 64 * wv + mi * 16 + l15;
#pragma unroll
        for (int jj = 0; jj < 8; ++jj) {
          const float v = kb[(size_t)(tok0 + kit * 32 + quad * 8 + jj) * kHalf + drow];
          fsplit(v, Ph.h[jj], Pl.h[jj]);
        }
        uah[mi * 2 + kit] = Ph.v;
        ual[mi * 2 + kit] = Pl.v;
      }
    __syncthreads();   // Rr/Gm visible

    // barrier-free triangular solve: thread j owns col j entirely
    if (tid < 64) {
      const int j = tid;
      for (int blk = 0; blk < 8; ++blk) {
        const int t0 = blk * 8;
        float rl[8], ub[8];
#pragma unroll
        for (int i = 0; i < 8; ++i) rl[i] = sh.b.Rr[t0 + i][j];
#pragma unroll
        for (int i = 0; i < 8; ++i) {
          const int t = t0 + i;
          const float kv = kb[(size_t)(tok0 + t) * kHalf + j0 + j];
          float u = wS[t] * kv - aS[t] * rl[i];
          if (ck == 15 && t == 63) u = 0.f;   // token L-1 is the query, no update
          ub[i] = u;
#pragma unroll
          for (int i2 = i + 1; i2 < 8; ++i2) rl[i2] += Gm[t0 + i2][t] * u;
        }
#pragma unroll
        for (int i = 0; i < 8; ++i) {
          const _Float16 h = (_Float16)ub[i];
          sh.b.Uh[j][t0 + i] = h;
          sh.b.Ul[j][t0 + i] = (_Float16)(ub[i] - (float)h);
        }
        for (int t2 = t0 + 8; t2 < 64; ++t2) {
          const float4 g0 = *(const float4*)&Gm[t2][t0];
          const float4 g1 = *(const float4*)&Gm[t2][t0 + 4];
          sh.b.Rr[t2][j] += g0.x*ub[0] + g0.y*ub[1] + g0.z*ub[2] + g0.w*ub[3]
                          + g1.x*ub[4] + g1.y*ub[5] + g1.z*ub[6] + g1.w*ub[7];
        }
      }
    }
    __syncthreads();   // Uh/Ul visible

    // S += K^T U  (A = K^T from regs, B = U from LDS)
#pragma unroll
    for (int kit = 0; kit < 2; ++kit) {
      const int ko = kit * 32 + quad * 8;
#pragma unroll
      for (int nt = 0; nt < 4; ++nt) {
        const f16x8 bh = *(const f16x8*)&sh.b.Uh[nt * 16 + l15][ko];
        const f16x8 bl = *(const f16x8*)&sh.b.Ul[nt * 16 + l15][ko];
#pragma unroll
        for (int mi = 0; mi < 4; ++mi) {
          f32x4 s = S[mi * 4 + nt];
          s = __builtin_amdgcn_mfma_f32_16x16x32_f16(uah[mi * 2 + kit], bh, s, 0, 0, 0);
          s = __builtin_amdgcn_mfma_f32_16x16x32_f16(uah[mi * 2 + kit], bl, s, 0, 0, 0);
          s = __builtin_amdgcn_mfma_f32_16x16x32_f16(ual[mi * 2 + kit], bh, s, 0, 0, 0);
          S[mi * 4 + nt] = s;
        }
      }
    }
  }

  // readout: c[col] = sum_rows S[row][col] * k_last[row]
  float part[4] = {0.f, 0.f, 0.f, 0.f};
#pragma unroll
  for (int mi = 0; mi < 4; ++mi) {
    float klr[4];
#pragma unroll
    for (int r = 0; r < 4; ++r)
      klr[r] = kb[(size_t)(kL - 1) * kHalf + 64 * wv + mi * 16 + quad * 4 + r];
#pragma unroll
    for (int nt = 0; nt < 4; ++nt)
#pragma unroll
      for (int r = 0; r < 4; ++r) part[nt] += S[mi * 4 + nt][r] * klr[r];
  }
#pragma unroll
  for (int nt = 0; nt < 4; ++nt) {
    part[nt] += __shfl_xor(part[nt], 16);
    part[nt] += __shfl_xor(part[nt], 32);
  }
  if (lane < 16) {
#pragma unroll
    for (int nt = 0; nt < 4; ++nt) cred[wv][nt * 16 + l15] = part[nt];
  }
  __syncthreads();
  if (tid < 64) {
    const float c = cred[0][tid] + cred[1][tid] + cred[2][tid] + cred[3][tid];
    c_out[(size_t)b * 512 + mat * 256 + j0 + tid] = c;
  }
}

// ---------------- output GEMM: (64 x 512) @ (512 x 32000) + out_b -> fp32
__global__ __launch_bounds__(256) void out_gemm(
    const float* __restrict__ A, const float* __restrict__ Bm,
    const float* __restrict__ bias, float* __restrict__ C)
{
  __shared__ float As[16][64];
  __shared__ float Bs[16][128];
  const int tid = threadIdx.x;
  const int bn0 = blockIdx.x * 128;
  const int tm = tid >> 4, tn = tid & 15;
  float acc[4][8];
#pragma unroll
  for (int i = 0; i < 4; ++i)
#pragma unroll
    for (int j = 0; j < 8; ++j) acc[i][j] = 0.f;

  const int am  = tid & 63;
  const int ak  = (tid >> 6) * 4;
  const int bkr = tid >> 5;
  const int bcg = (tid & 31) * 4;

  for (int k0 = 0; k0 < kH; k0 += 16) {
    const float4 a0 = *(const float4*)(A + (size_t)am * kH + k0 + ak);
    const float4 b0 = *(const float4*)(Bm + (size_t)(k0 + bkr) * kV + bn0 + bcg);
    const float4 b1 = *(const float4*)(Bm + (size_t)(k0 + bkr + 8) * kV + bn0 + bcg);
    __syncthreads();
    As[ak + 0][am] = a0.x; As[ak + 1][am] = a0.y;
    As[ak + 2][am] = a0.z; As[ak + 3][am] = a0.w;
    *(float4*)&Bs[bkr][bcg]     = b0;
    *(float4*)&Bs[bkr + 8][bcg] = b1;
    __syncthreads();
#pragma unroll
    for (int kk = 0; kk < 16; ++kk) {
      const float4 aA = *(const float4*)&As[kk][tm * 4];
      const float4 bA = *(const float4*)&Bs[kk][tn * 4];
      const float4 bB = *(const float4*)&Bs[kk][64 + tn * 4];
      const float av[4] = {aA.x, aA.y, aA.z, aA.w};
      const float bv[8] = {bA.x, bA.y, bA.z, bA.w, bB.x, bB.y, bB.z, bB.w};
#pragma unroll
      for (int i = 0; i < 4; ++i)
#pragma unroll
        for (int j = 0; j < 8; ++j) acc[i][j] += av[i] * bv[j];
    }
  }

#pragma unroll
  for (int i = 0; i < 4; ++i) {
    const int row = tm * 4 + i;
#pragma unroll
    for (int hh = 0; hh < 2; ++hh) {
      const int n0 = bn0 + tn * 4 + hh * 64;
      const float4 bb = *(const float4*)(bias + n0);
      float4 o;
      o.x = acc[i][hh * 4 + 0] + bb.x;
      o.y = acc[i][hh * 4 + 1] + bb.y;
      o.z = acc[i][hh * 4 + 2] + bb.z;
      o.w = acc[i][hh * 4 + 3] + bb.w;
      *(float4*)(C + (size_t)row * kV + n0) = o;
    }
  }
}

}  // namespace

extern "C" void kernel_launch(void* const* d_in, const int* in_sizes, int n_in,
                              void* d_out, int out_size, void* d_ws, size_t ws_size,
                              hipStream_t stream)
{
  const int*   seq     = (const int*)  d_in[0];
  const float* embed   = (const float*)d_in[1];
  const float* w1      = (const float*)d_in[2];
  const float* b1      = (const float*)d_in[3];
  const float* w2      = (const float*)d_in[4];
  const float* b2      = (const float*)d_in[5];
  const float* ln_g    = (const float*)d_in[6];
  const float* ln_b    = (const float*)d_in[7];
  const float* sem_w   = (const float*)d_in[8];
  const float* sem_b   = (const float*)d_in[9];
  const float* epi_w   = (const float*)d_in[10];
  const float* epi_b   = (const float*)d_in[11];
  const float* out_w   = (const float*)d_in[12];
  const float* out_b   = (const float*)d_in[13];
  const float* pos_emb = (const float*)d_in[14];
  const float* pos_w   = (const float*)d_in[15];
  const float* pos_b   = (const float*)d_in[16];
  float* out = (float*)d_out;

  // ---- workspace layout: 207.2 MB (known-good bound)
  char* p = (char*)d_ws;
  _Float16* w1th = (_Float16*)p; p += (size_t)1024 * 512 * 2;
  _Float16* w1tl = (_Float16*)p; p += (size_t)1024 * 512 * 2;
  _Float16* w2th = (_Float16*)p; p += (size_t)512 * 1024 * 2;
  _Float16* w2tl = (_Float16*)p; p += (size_t)512 * 1024 * 2;
  _Float16* wseh = (_Float16*)p; p += (size_t)512 * 512 * 2;
  _Float16* wsel = (_Float16*)p; p += (size_t)512 * 512 * 2;
  _Float16* eh   = (_Float16*)p; p += (size_t)kChunk * kH * 2;
  _Float16* el   = (_Float16*)p; p += (size_t)kChunk * kH * 2;
  _Float16* t1h  = (_Float16*)p; p += (size_t)kChunk * 1024 * 2;
  _Float16* t1l  = (_Float16*)p; p += (size_t)kChunk * 1024 * 2;
  float*    x    = (float*)p;    p += (size_t)kChunk * kH * 4;
  float*    ks   = (float*)p;    p += (size_t)kTok * kHalf * 4;
  float*    ke   = (float*)p;    p += (size_t)kTok * kHalf * 4;
  float*    invs = (float*)p;    p += (size_t)kTok * 4;
  float*    inve = (float*)p;    p += (size_t)kTok * 4;
  float*    wts  = (float*)p;    p += (size_t)kL * 4;
  float*    cout_= (float*)p;    p += (size_t)kB * 512 * 4;
  _Float16* hh   = t1h;          // alias: t1 dead once x is written
  _Float16* hl   = t1l;

  pos_kernel<<<dim3((kL + 255) / 256), dim3(256), 0, stream>>>(pos_emb, pos_w, pos_b, wts);
  transpose_split<<<dim3(1024 * 512 / 256), dim3(256), 0, stream>>>(w1, w1th, w1tl, 1024, 9);
  transpose_split<<<dim3(512 * 1024 / 256), dim3(256), 0, stream>>>(w2, w2th, w2tl, 512, 10);
  transpose_split<<<dim3(256 * 512 / 256), dim3(256), 0, stream>>>(sem_w, wseh, wsel, 256, 9);
  transpose_split<<<dim3(256 * 512 / 256), dim3(256), 0, stream>>>(
      epi_w, wseh + (size_t)256 * 512, wsel + (size_t)256 * 512, 256, 9);

  for (int c = 0; c < kTok / kChunk; ++c) {
    const int tok0 = c * kChunk;
    gather_split<<<dim3(kChunk / 4), dim3(256), 0, stream>>>(seq, embed, eh, el, tok0);
    hgemm<0><<<dim3(1024 / 128, kChunk / 128), dim3(256), 0, stream>>>(
        eh, el, w1th, w1tl, b1, nullptr, nullptr, nullptr,
        nullptr, t1h, t1l, nullptr, nullptr, 512, 1024);
    hgemm<1><<<dim3(512 / 128, kChunk / 128), dim3(256), 0, stream>>>(
        t1h, t1l, w2th, w2tl, b2, nullptr, eh, el,
        x, nullptr, nullptr, nullptr, nullptr, 1024, 512);
    ln_split<<<dim3(kChunk / 4), dim3(256), 0, stream>>>(x, ln_g, ln_b, hh, hl);
    hgemm<2><<<dim3(512 / 128, kChunk / 128), dim3(256), 0, stream>>>(
        hh, hl, wseh, wsel, sem_b, epi_b, nullptr, nullptr,
        nullptr, nullptr, nullptr, ks + (size_t)tok0 * kHalf, ke + (size_t)tok0 * kHalf,
        512, 512);
    invnorm_kernel<<<dim3(kChunk / 4), dim3(256), 0, stream>>>(ks, ke, invs, inve, tok0);
  }

  scan_chunked<<<dim3(512), dim3(256), 0, stream>>>(ks, ke, invs, inve, wts, cout_);
  out_gemm<<<dim3(kV / 128), dim3(256), 0, stream>>>(cout_, out_w, out_b, out);

  (void)in_sizes; (void)n_in; (void)out_size; (void)ws_size;
}

// Round 6
// 1814.849 us; speedup vs baseline: 1.8180x; 1.0284x over previous
//
#include <hip/hip_runtime.h>
#include <hip/hip_bf16.h>
#include <math.h>

namespace {

constexpr int kH     = 512;
constexpr int kL     = 1024;
constexpr int kB     = 64;
constexpr int kHalf  = 256;
constexpr int kV     = 32000;
constexpr int kTok   = kB * kL;     // 65536

using f32x4 = __attribute__((ext_vector_type(4))) float;
using f16x8 = __attribute__((ext_vector_type(8))) _Float16;

__device__ inline void fsplit(float v, _Float16& h, _Float16& l) {
  h = (_Float16)v;
  l = (_Float16)(v - (float)h);
}

// ---------------- positional weights
__global__ void pos_kernel(const float* __restrict__ pos_emb,
                           const float* __restrict__ pos_w,
                           const float* __restrict__ pos_b,
                           float* __restrict__ wts)
{
  int t = blockIdx.x * blockDim.x + threadIdx.x;
  if (t >= kL) return;
  float z = pos_b[0];
#pragma unroll
  for (int p = 0; p < 16; ++p) z += pos_emb[t * 16 + p] * pos_w[p];
  wts[t] = 1.f / (1.f + expf(-z));
}

// ---------------- transpose + hi/lo fp16 split: W[K][N] fp32 -> Th/Tl[N][K]
__global__ __launch_bounds__(256) void transpose_split(
    const float* __restrict__ W, _Float16* __restrict__ Th,
    _Float16* __restrict__ Tl, int N, int kshift)
{
  const int idx = blockIdx.x * 256 + threadIdx.x;
  const int K = 1 << kshift;
  const int k = idx & (K - 1);
  const int n = idx >> kshift;
  const float w = W[(size_t)k * N + n];
  const _Float16 h = (_Float16)w;
  Th[idx] = h;
  Tl[idx] = (_Float16)(w - (float)h);
}

// ---------------- split-fp16 MFMA GEMM: C[M,N] = A[M,K] @ (Bh+Bl)[N,K]^T
// EPI 0: A gathered from embed[seq[.]] (fp32, split on the fly); relu(acc+bias)
//        -> hi/lo fp16 Oh/Ol (ld N)
// EPI 1: A = Ah/Al; acc + bias + embed[seq[gm]][gn] (exact resid) -> fp32 Xout
// EPI 2: A = Ah/Al; acc + (n<256 ? bias : bias2) -> ks/ke fp32 (ld 256)
template <int EPI>
__global__ __launch_bounds__(256) void hgemm(
    const int* __restrict__ seq, const float* __restrict__ embed,
    const _Float16* __restrict__ Ah, const _Float16* __restrict__ Al,
    const _Float16* __restrict__ Bh, const _Float16* __restrict__ Bl,
    const float* __restrict__ bias, const float* __restrict__ bias2,
    float* __restrict__ Xout, _Float16* __restrict__ Oh, _Float16* __restrict__ Ol,
    float* __restrict__ ks, float* __restrict__ ke,
    int K, int N, int tok0c)
{
  __shared__ _Float16 lds[4][128][40];   // Ahi, Alo, Bhi, Blo; +8 pad (80B stride)
  const int tid  = threadIdx.x;
  const int lane = tid & 63;
  const int wv   = tid >> 6;
  const int wm   = (wv >> 1) * 64;
  const int wn   = (wv & 1) * 64;
  const int bm0  = blockIdx.y * 128;
  const int bn0  = blockIdx.x * 128;

  f32x4 acc[4][4];
#pragma unroll
  for (int i = 0; i < 4; ++i)
#pragma unroll
    for (int j = 0; j < 4; ++j) acc[i][j] = {0.f, 0.f, 0.f, 0.f};

  const int sr = tid >> 1;            // staging row 0..127
  const int sc = (tid & 1) << 4;      // 0 or 16 (halves)
  const _Float16* gBh = Bh + (size_t)(bn0 + sr) * K + sc;
  const _Float16* gBl = Bl + (size_t)(bn0 + sr) * K + sc;
  const _Float16* gAh = nullptr;
  const _Float16* gAl = nullptr;
  const float*    gAe = nullptr;
  if constexpr (EPI == 0) {
    const int tokrow = seq[tok0c + bm0 + sr];
    gAe = embed + (size_t)tokrow * kH + sc;
  } else {
    gAh = Ah + (size_t)(bm0 + sr) * K + sc;
    gAl = Al + (size_t)(bm0 + sr) * K + sc;
  }

  const int lrow = lane & 15;
  const int lk   = (lane >> 4) * 8;

  for (int k0 = 0; k0 < K; k0 += 32) {
    const uint4 vC0 = *(const uint4*)(gBh + k0);
    const uint4 vC1 = *(const uint4*)(gBh + k0 + 8);
    const uint4 vD0 = *(const uint4*)(gBl + k0);
    const uint4 vD1 = *(const uint4*)(gBl + k0 + 8);
    if constexpr (EPI == 0) {
      const float4 a0 = *(const float4*)(gAe + k0);
      const float4 a1 = *(const float4*)(gAe + k0 + 4);
      const float4 a2 = *(const float4*)(gAe + k0 + 8);
      const float4 a3 = *(const float4*)(gAe + k0 + 12);
      const float vv[16] = {a0.x,a0.y,a0.z,a0.w, a1.x,a1.y,a1.z,a1.w,
                            a2.x,a2.y,a2.z,a2.w, a3.x,a3.y,a3.z,a3.w};
      union { _Float16 h[16]; uint4 u[2]; } ph, pl;
#pragma unroll
      for (int i = 0; i < 16; ++i) fsplit(vv[i], ph.h[i], pl.h[i]);
      __syncthreads();
      *(uint4*)&lds[0][sr][sc]     = ph.u[0];
      *(uint4*)&lds[0][sr][sc + 8] = ph.u[1];
      *(uint4*)&lds[1][sr][sc]     = pl.u[0];
      *(uint4*)&lds[1][sr][sc + 8] = pl.u[1];
    } else {
      const uint4 vA0 = *(const uint4*)(gAh + k0);
      const uint4 vA1 = *(const uint4*)(gAh + k0 + 8);
      const uint4 vB0 = *(const uint4*)(gAl + k0);
      const uint4 vB1 = *(const uint4*)(gAl + k0 + 8);
      __syncthreads();
      *(uint4*)&lds[0][sr][sc]     = vA0;
      *(uint4*)&lds[0][sr][sc + 8] = vA1;
      *(uint4*)&lds[1][sr][sc]     = vB0;
      *(uint4*)&lds[1][sr][sc + 8] = vB1;
    }
    *(uint4*)&lds[2][sr][sc]     = vC0;
    *(uint4*)&lds[2][sr][sc + 8] = vC1;
    *(uint4*)&lds[3][sr][sc]     = vD0;
    *(uint4*)&lds[3][sr][sc + 8] = vD1;
    __syncthreads();

    f16x8 fBh[4], fBl[4];
#pragma unroll
    for (int ni = 0; ni < 4; ++ni) {
      fBh[ni] = *(const f16x8*)&lds[2][wn + ni * 16 + lrow][lk];
      fBl[ni] = *(const f16x8*)&lds[3][wn + ni * 16 + lrow][lk];
    }
#pragma unroll
    for (int mi = 0; mi < 4; ++mi) {
      const f16x8 ah = *(const f16x8*)&lds[0][wm + mi * 16 + lrow][lk];
      const f16x8 al = *(const f16x8*)&lds[1][wm + mi * 16 + lrow][lk];
#pragma unroll
      for (int ni = 0; ni < 4; ++ni) {
        acc[mi][ni] = __builtin_amdgcn_mfma_f32_16x16x32_f16(ah, fBh[ni], acc[mi][ni], 0, 0, 0);
        acc[mi][ni] = __builtin_amdgcn_mfma_f32_16x16x32_f16(ah, fBl[ni], acc[mi][ni], 0, 0, 0);
        acc[mi][ni] = __builtin_amdgcn_mfma_f32_16x16x32_f16(al, fBh[ni], acc[mi][ni], 0, 0, 0);
      }
    }
  }

  // epilogue: D col = lane&15, row = (lane>>4)*4 + reg
  const int erow0 = (lane >> 4) * 4;
  if constexpr (EPI == 0) {
#pragma unroll
    for (int mi = 0; mi < 4; ++mi)
#pragma unroll
      for (int ni = 0; ni < 4; ++ni) {
        const int gn = bn0 + wn + ni * 16 + (lane & 15);
        const float bv = bias[gn];
#pragma unroll
        for (int r = 0; r < 4; ++r) {
          const int gm = bm0 + wm + mi * 16 + erow0 + r;
          float v = fmaxf(acc[mi][ni][r] + bv, 0.f);
          const _Float16 h = (_Float16)v;
          Oh[(size_t)gm * N + gn] = h;
          Ol[(size_t)gm * N + gn] = (_Float16)(v - (float)h);
        }
      }
  } else if constexpr (EPI == 1) {
#pragma unroll
    for (int mi = 0; mi < 4; ++mi)
#pragma unroll
      for (int r = 0; r < 4; ++r) {
        const int gm = bm0 + wm + mi * 16 + erow0 + r;
        const int tok = seq[tok0c + gm];
        const float* er = embed + (size_t)tok * kH;
#pragma unroll
        for (int ni = 0; ni < 4; ++ni) {
          const int gn = bn0 + wn + ni * 16 + (lane & 15);
          Xout[(size_t)gm * N + gn] = acc[mi][ni][r] + bias[gn] + er[gn];
        }
      }
  } else {
#pragma unroll
    for (int mi = 0; mi < 4; ++mi)
#pragma unroll
      for (int ni = 0; ni < 4; ++ni) {
        const int gn = bn0 + wn + ni * 16 + (lane & 15);
        const float bv = (gn < 256) ? bias[gn] : bias2[gn - 256];
#pragma unroll
        for (int r = 0; r < 4; ++r) {
          const int gm = bm0 + wm + mi * 16 + erow0 + r;
          const float v = acc[mi][ni][r] + bv;
          if (gn < 256) ks[(size_t)gm * 256 + gn] = v;
          else          ke[(size_t)gm * 256 + (gn - 256)] = v;
        }
      }
  }
}

// ---------------- LayerNorm: x fp32 -> hi/lo fp16
__global__ __launch_bounds__(256) void ln_split(
    const float* __restrict__ x, const float* __restrict__ g,
    const float* __restrict__ bta, _Float16* __restrict__ hh,
    _Float16* __restrict__ hl)
{
  const int wid  = threadIdx.x >> 6;
  const int lane = threadIdx.x & 63;
  const int ltok = blockIdx.x * 4 + wid;
  const float* xp = x + (size_t)ltok * kH;
  const float4 v0 = *(const float4*)(xp + lane * 8);
  const float4 v1 = *(const float4*)(xp + lane * 8 + 4);
  float s  = v0.x + v0.y + v0.z + v0.w + v1.x + v1.y + v1.z + v1.w;
  float ss = v0.x * v0.x + v0.y * v0.y + v0.z * v0.z + v0.w * v0.w +
             v1.x * v1.x + v1.y * v1.y + v1.z * v1.z + v1.w * v1.w;
#pragma unroll
  for (int m = 1; m < 64; m <<= 1) { s += __shfl_xor(s, m); ss += __shfl_xor(ss, m); }
  const float mu  = s * (1.f / kH);
  const float var = ss * (1.f / kH) - mu * mu;
  const float rs  = 1.f / sqrtf(var + 1e-5f);
  const float4 g0 = *(const float4*)(g + lane * 8);
  const float4 g1 = *(const float4*)(g + lane * 8 + 4);
  const float4 b0 = *(const float4*)(bta + lane * 8);
  const float4 b1 = *(const float4*)(bta + lane * 8 + 4);
  const float vv[8] = {v0.x, v0.y, v0.z, v0.w, v1.x, v1.y, v1.z, v1.w};
  const float gg[8] = {g0.x, g0.y, g0.z, g0.w, g1.x, g1.y, g1.z, g1.w};
  const float bb[8] = {b0.x, b0.y, b0.z, b0.w, b1.x, b1.y, b1.z, b1.w};
  union { _Float16 h[8]; uint4 u; } ph, pl;
#pragma unroll
  for (int i = 0; i < 8; ++i) {
    const float o = (vv[i] - mu) * rs * gg[i] + bb[i];
    fsplit(o, ph.h[i], pl.h[i]);
  }
  *(uint4*)(hh + (size_t)ltok * kH + lane * 8) = ph.u;
  *(uint4*)(hl + (size_t)ltok * kH + lane * 8) = pl.u;
}

// ---------------- chunked WY delta-rule scan (v3).
// Changes vs v2: Kq fp32 panel in LDS (solve reads LDS not global);
// packed 16B U stores (conflict-free); panel-load prefetch pipelined under
// MFMA; invnorm fused into staging (register ssq + 2-shuffle reduce).
struct PhaseA { _Float16 Kph[64][72], Kpl[64][72], Sph[64][72], Spl[64][72]; };
struct PhaseB { float Rr[64][68]; _Float16 Uh[64][72], Ul[64][72]; };
union ShU { PhaseA a; PhaseB b; };

__global__ __launch_bounds__(256, 2) void scan_chunked(
    const float* __restrict__ ks, const float* __restrict__ ke,
    const float* __restrict__ wts, float* __restrict__ c_out)
{
  __shared__ ShU sh;
  __shared__ float Gm[64][68];   // Gm[x][y] = k_x . k_y
  __shared__ float Kq[64][65];   // this WG's fp32 K column-panel (bank (t+j)%32)
  __shared__ float aS[64], wS[64];
  __shared__ float cred[4][64];

  const int tid  = threadIdx.x;
  const int lane = tid & 63;
  const int wv   = tid >> 6;
  const int l15  = lane & 15;
  const int quad = lane >> 4;
  const int wg   = blockIdx.x;
  const int b    = wg >> 3;
  const int mat  = (wg >> 2) & 1;
  const int q    = wg & 3;
  const int j0   = q * 64;
  const float* kb = (mat ? ke : ks) + (size_t)b * ((size_t)kL * kHalf);

  f32x4 S[16];
#pragma unroll
  for (int i = 0; i < 16; ++i) S[i] = {0.f, 0.f, 0.f, 0.f};

  const int stk = tid >> 2;          // staging token 0..63
  const int dg  = (tid & 3) * 16;    // staging col group

  float4 pv0, pv1, pv2, pv3;
  auto issue = [&](int ckk, int pp) {
    const float* src = kb + (size_t)(ckk * 64 + stk) * kHalf + pp * 64 + dg;
    pv0 = *(const float4*)(src);
    pv1 = *(const float4*)(src + 4);
    pv2 = *(const float4*)(src + 8);
    pv3 = *(const float4*)(src + 12);
  };
  issue(0, 0);

  for (int ck = 0; ck < 16; ++ck) {
    const int tok0 = ck * 64;
    float ssq = 0.f;
    f32x4 Qa[4], Ga[4];
#pragma unroll
    for (int i = 0; i < 4; ++i) { Qa[i] = {0.f,0.f,0.f,0.f}; Ga[i] = {0.f,0.f,0.f,0.f}; }

    for (int p = 0; p < 4; ++p) {
      __syncthreads();   // prior LDS readers done (MFMA / prior-chunk S-update)
      {  // consume prefetched K panel
        const float vv[16] = {pv0.x,pv0.y,pv0.z,pv0.w, pv1.x,pv1.y,pv1.z,pv1.w,
                              pv2.x,pv2.y,pv2.z,pv2.w, pv3.x,pv3.y,pv3.z,pv3.w};
        union { _Float16 h[16]; uint4 u[2]; } ph, pl;
#pragma unroll
        for (int i = 0; i < 16; ++i) fsplit(vv[i], ph.h[i], pl.h[i]);
        *(uint4*)&sh.a.Kph[stk][dg]     = ph.u[0];
        *(uint4*)&sh.a.Kph[stk][dg + 8] = ph.u[1];
        *(uint4*)&sh.a.Kpl[stk][dg]     = pl.u[0];
        *(uint4*)&sh.a.Kpl[stk][dg + 8] = pl.u[1];
        if (p == q) {
          *(float4*)&Kq[stk][dg]      = pv0;
          *(float4*)&Kq[stk][dg + 4]  = pv1;
          *(float4*)&Kq[stk][dg + 8]  = pv2;
          *(float4*)&Kq[stk][dg + 12] = pv3;
        }
#pragma unroll
        for (int i = 0; i < 16; ++i) ssq += vv[i] * vv[i];
      }
      if (wv == p) {  // stage S panel p (rows 64p..64p+63): [col][row] hi/lo
#pragma unroll
        for (int mi = 0; mi < 4; ++mi)
#pragma unroll
          for (int nt = 0; nt < 4; ++nt) {
            const f32x4 v = S[mi * 4 + nt];
            union { _Float16 h[4]; uint2 u; } qh, ql;
#pragma unroll
            for (int r = 0; r < 4; ++r) fsplit(v[r], qh.h[r], ql.h[r]);
            *(uint2*)&sh.a.Sph[nt * 16 + l15][mi * 16 + quad * 4] = qh.u;
            *(uint2*)&sh.a.Spl[nt * 16 + l15][mi * 16 + quad * 4] = ql.u;
          }
      }
      __syncthreads();
      if (p < 3) issue(ck, p + 1);   // prefetch next panel under MFMA
#pragma unroll
      for (int kit = 0; kit < 2; ++kit) {
        const int ko = kit * 32 + quad * 8;
        const f16x8 ah = *(const f16x8*)&sh.a.Kph[wv * 16 + l15][ko];
        const f16x8 al = *(const f16x8*)&sh.a.Kpl[wv * 16 + l15][ko];
#pragma unroll
        for (int nt = 0; nt < 4; ++nt) {
          const f16x8 bh = *(const f16x8*)&sh.a.Sph[nt * 16 + l15][ko];
          const f16x8 bl = *(const f16x8*)&sh.a.Spl[nt * 16 + l15][ko];
          Qa[nt] = __builtin_amdgcn_mfma_f32_16x16x32_f16(ah, bh, Qa[nt], 0, 0, 0);
          Qa[nt] = __builtin_amdgcn_mfma_f32_16x16x32_f16(ah, bl, Qa[nt], 0, 0, 0);
          Qa[nt] = __builtin_amdgcn_mfma_f32_16x16x32_f16(al, bh, Qa[nt], 0, 0, 0);
        }
#pragma unroll
        for (int nt = 0; nt < 4; ++nt) {
          const f16x8 bh = *(const f16x8*)&sh.a.Kph[nt * 16 + l15][ko];
          const f16x8 bl = *(const f16x8*)&sh.a.Kpl[nt * 16 + l15][ko];
          Ga[nt] = __builtin_amdgcn_mfma_f32_16x16x32_f16(ah, bh, Ga[nt], 0, 0, 0);
          Ga[nt] = __builtin_amdgcn_mfma_f32_16x16x32_f16(ah, bl, Ga[nt], 0, 0, 0);
          Ga[nt] = __builtin_amdgcn_mfma_f32_16x16x32_f16(al, bh, Ga[nt], 0, 0, 0);
        }
      }
    }

    // fused invnorm: reduce ssq over the 4 dg-lanes of each token
    ssq += __shfl_xor(ssq, 1);
    ssq += __shfl_xor(ssq, 2);
    if ((tid & 3) == 0) {
      const float w = mat ? wts[tok0 + stk] : 1.f;
      wS[stk] = w;
      aS[stk] = w / (ssq + 1e-6f);
    }
    __syncthreads();   // panel LDS reads done -> safe to write aliased Rr; aS/wS visible

    // Q -> Rr[t][col] ; G -> Gm
#pragma unroll
    for (int nt = 0; nt < 4; ++nt) {
#pragma unroll
      for (int r = 0; r < 4; ++r)
        sh.b.Rr[wv * 16 + quad * 4 + r][nt * 16 + l15] = Qa[nt][r];
      *(float4*)&Gm[nt * 16 + l15][wv * 16 + quad * 4] = *(const float4*)&Ga[nt];
    }
    // prefetch S-update A-fragments (K^T), consumed after the solve
    f16x8 uah[8], ual[8];
#pragma unroll
    for (int mi = 0; mi < 4; ++mi)
#pragma unroll
      for (int kit = 0; kit < 2; ++kit) {
        union { _Float16 h[8]; f16x8 v; } Ph, Pl;
        const int drow = 64 * wv + mi * 16 + l15;
#pragma unroll
        for (int jj = 0; jj < 8; ++jj) {
          const float v = kb[(size_t)(tok0 + kit * 32 + quad * 8 + jj) * kHalf + drow];
          fsplit(v, Ph.h[jj], Pl.h[jj]);
        }
        uah[mi * 2 + kit] = Ph.v;
        ual[mi * 2 + kit] = Pl.v;
      }
    __syncthreads();   // Rr/Gm visible

    // barrier-free triangular solve: thread j owns col j; all operands in LDS
    if (tid < 64) {
      const int j = tid;
      for (int blk = 0; blk < 8; ++blk) {
        const int t0 = blk * 8;
        float rl[8], kv[8], ub[8];
#pragma unroll
        for (int i = 0; i < 8; ++i) rl[i] = sh.b.Rr[t0 + i][j];
#pragma unroll
        for (int i = 0; i < 8; ++i) kv[i] = Kq[t0 + i][j];
#pragma unroll
        for (int i = 0; i < 8; ++i) {
          const int t = t0 + i;
          float u = wS[t] * kv[i] - aS[t] * rl[i];
          if (ck == 15 && t == 63) u = 0.f;   // token L-1 is the query only
          ub[i] = u;
#pragma unroll
          for (int i2 = i + 1; i2 < 8; ++i2) rl[i2] += Gm[t0 + i2][t] * u;
        }
        union { _Float16 h[8]; uint4 u4; } uh, ul;
#pragma unroll
        for (int i = 0; i < 8; ++i) fsplit(ub[i], uh.h[i], ul.h[i]);
        *(uint4*)&sh.b.Uh[j][t0] = uh.u4;    // 16B packed: conflict-free
        *(uint4*)&sh.b.Ul[j][t0] = ul.u4;
        for (int t2 = t0 + 8; t2 < 64; ++t2) {
          const float4 g0 = *(const float4*)&Gm[t2][t0];
          const float4 g1 = *(const float4*)&Gm[t2][t0 + 4];
          sh.b.Rr[t2][j] += g0.x*ub[0] + g0.y*ub[1] + g0.z*ub[2] + g0.w*ub[3]
                          + g1.x*ub[4] + g1.y*ub[5] + g1.z*ub[6] + g1.w*ub[7];
        }
      }
    }
    __syncthreads();   // Uh/Ul visible
    if (ck < 15) issue(ck + 1, 0);   // prefetch next chunk under S-update

    // S += K^T U
#pragma unroll
    for (int kit = 0; kit < 2; ++kit) {
      const int ko = kit * 32 + quad * 8;
#pragma unroll
      for (int nt = 0; nt < 4; ++nt) {
        const f16x8 bh = *(const f16x8*)&sh.b.Uh[nt * 16 + l15][ko];
        const f16x8 bl = *(const f16x8*)&sh.b.Ul[nt * 16 + l15][ko];
#pragma unroll
        for (int mi = 0; mi < 4; ++mi) {
          f32x4 s = S[mi * 4 + nt];
          s = __builtin_amdgcn_mfma_f32_16x16x32_f16(uah[mi * 2 + kit], bh, s, 0, 0, 0);
          s = __builtin_amdgcn_mfma_f32_16x16x32_f16(uah[mi * 2 + kit], bl, s, 0, 0, 0);
          s = __builtin_amdgcn_mfma_f32_16x16x32_f16(ual[mi * 2 + kit], bh, s, 0, 0, 0);
          S[mi * 4 + nt] = s;
        }
      }
    }
  }

  // readout: c[col] = sum_rows S[row][col] * k_last[row]
  float part[4] = {0.f, 0.f, 0.f, 0.f};
#pragma unroll
  for (int mi = 0; mi < 4; ++mi) {
    float klr[4];
#pragma unroll
    for (int r = 0; r < 4; ++r)
      klr[r] = kb[(size_t)(kL - 1) * kHalf + 64 * wv + mi * 16 + quad * 4 + r];
#pragma unroll
    for (int nt = 0; nt < 4; ++nt)
#pragma unroll
      for (int r = 0; r < 4; ++r) part[nt] += S[mi * 4 + nt][r] * klr[r];
  }
#pragma unroll
  for (int nt = 0; nt < 4; ++nt) {
    part[nt] += __shfl_xor(part[nt], 16);
    part[nt] += __shfl_xor(part[nt], 32);
  }
  if (lane < 16) {
#pragma unroll
    for (int nt = 0; nt < 4; ++nt) cred[wv][nt * 16 + l15] = part[nt];
  }
  __syncthreads();
  if (tid < 64) {
    const float c = cred[0][tid] + cred[1][tid] + cred[2][tid] + cred[3][tid];
    c_out[(size_t)b * 512 + mat * 256 + j0 + tid] = c;
  }
}

// ---------------- output GEMM: (64 x 512) @ (512 x 32000) + out_b -> fp32
__global__ __launch_bounds__(256) void out_gemm(
    const float* __restrict__ A, const float* __restrict__ Bm,
    const float* __restrict__ bias, float* __restrict__ C)
{
  __shared__ float As[16][64];
  __shared__ float Bs[16][128];
  const int tid = threadIdx.x;
  const int bn0 = blockIdx.x * 128;
  const int tm = tid >> 4, tn = tid & 15;
  float acc[4][8];
#pragma unroll
  for (int i = 0; i < 4; ++i)
#pragma unroll
    for (int j = 0; j < 8; ++j) acc[i][j] = 0.f;

  const int am  = tid & 63;
  const int ak  = (tid >> 6) * 4;
  const int bkr = tid >> 5;
  const int bcg = (tid & 31) * 4;

  for (int k0 = 0; k0 < kH; k0 += 16) {
    const float4 a0 = *(const float4*)(A + (size_t)am * kH + k0 + ak);
    const float4 b0 = *(const float4*)(Bm + (size_t)(k0 + bkr) * kV + bn0 + bcg);
    const float4 b1 = *(const float4*)(Bm + (size_t)(k0 + bkr + 8) * kV + bn0 + bcg);
    __syncthreads();
    As[ak + 0][am] = a0.x; As[ak + 1][am] = a0.y;
    As[ak + 2][am] = a0.z; As[ak + 3][am] = a0.w;
    *(float4*)&Bs[bkr][bcg]     = b0;
    *(float4*)&Bs[bkr + 8][bcg] = b1;
    __syncthreads();
#pragma unroll
    for (int kk = 0; kk < 16; ++kk) {
      const float4 aA = *(const float4*)&As[kk][tm * 4];
      const float4 bA = *(const float4*)&Bs[kk][tn * 4];
      const float4 bB = *(const float4*)&Bs[kk][64 + tn * 4];
      const float av[4] = {aA.x, aA.y, aA.z, aA.w};
      const float bv[8] = {bA.x, bA.y, bA.z, bA.w, bB.x, bB.y, bB.z, bB.w};
#pragma unroll
      for (int i = 0; i < 4; ++i)
#pragma unroll
        for (int j = 0; j < 8; ++j) acc[i][j] += av[i] * bv[j];
    }
  }

#pragma unroll
  for (int i = 0; i < 4; ++i) {
    const int row = tm * 4 + i;
#pragma unroll
    for (int hh = 0; hh < 2; ++hh) {
      const int n0 = bn0 + tn * 4 + hh * 64;
      const float4 bb = *(const float4*)(bias + n0);
      float4 o;
      o.x = acc[i][hh * 4 + 0] + bb.x;
      o.y = acc[i][hh * 4 + 1] + bb.y;
      o.z = acc[i][hh * 4 + 2] + bb.z;
      o.w = acc[i][hh * 4 + 3] + bb.w;
      *(float4*)(C + (size_t)row * kV + n0) = o;
    }
  }
}

}  // namespace

extern "C" void kernel_launch(void* const* d_in, const int* in_sizes, int n_in,
                              void* d_out, int out_size, void* d_ws, size_t ws_size,
                              hipStream_t stream)
{
  const int*   seq     = (const int*)  d_in[0];
  const float* embed   = (const float*)d_in[1];
  const float* w1      = (const float*)d_in[2];
  const float* b1      = (const float*)d_in[3];
  const float* w2      = (const float*)d_in[4];
  const float* b2      = (const float*)d_in[5];
  const float* ln_g    = (const float*)d_in[6];
  const float* ln_b    = (const float*)d_in[7];
  const float* sem_w   = (const float*)d_in[8];
  const float* sem_b   = (const float*)d_in[9];
  const float* epi_w   = (const float*)d_in[10];
  const float* epi_b   = (const float*)d_in[11];
  const float* out_w   = (const float*)d_in[12];
  const float* out_b   = (const float*)d_in[13];
  const float* pos_emb = (const float*)d_in[14];
  const float* pos_w   = (const float*)d_in[15];
  const float* pos_b   = (const float*)d_in[16];
  float* out = (float*)d_out;

  // chunk size: 16384 needs 240.3 MB of ws; fall back to 8192 (190 MB) if tight.
  // ws_size is constant per process -> deterministic, graph-capture-safe.
  const int chunkN = (ws_size >= (size_t)240500000) ? 16384 : 8192;
  const int nch    = kTok / chunkN;

  char* p = (char*)d_ws;
  _Float16* w1th = (_Float16*)p; p += (size_t)1024 * 512 * 2;
  _Float16* w1tl = (_Float16*)p; p += (size_t)1024 * 512 * 2;
  _Float16* w2th = (_Float16*)p; p += (size_t)512 * 1024 * 2;
  _Float16* w2tl = (_Float16*)p; p += (size_t)512 * 1024 * 2;
  _Float16* wseh = (_Float16*)p; p += (size_t)512 * 512 * 2;
  _Float16* wsel = (_Float16*)p; p += (size_t)512 * 512 * 2;
  _Float16* t1h  = (_Float16*)p; p += (size_t)chunkN * 1024 * 2;
  _Float16* t1l  = (_Float16*)p; p += (size_t)chunkN * 1024 * 2;
  float*    x    = (float*)p;    p += (size_t)chunkN * kH * 4;
  float*    ks   = (float*)p;    p += (size_t)kTok * kHalf * 4;
  float*    ke   = (float*)p;    p += (size_t)kTok * kHalf * 4;
  float*    wts  = (float*)p;    p += (size_t)kL * 4;
  float*    cout_= (float*)p;    p += (size_t)kB * 512 * 4;
  _Float16* hh   = t1h;          // alias: t1 dead once x is written
  _Float16* hl   = t1l;

  pos_kernel<<<dim3((kL + 255) / 256), dim3(256), 0, stream>>>(pos_emb, pos_w, pos_b, wts);
  transpose_split<<<dim3(1024 * 512 / 256), dim3(256), 0, stream>>>(w1, w1th, w1tl, 1024, 9);
  transpose_split<<<dim3(512 * 1024 / 256), dim3(256), 0, stream>>>(w2, w2th, w2tl, 512, 10);
  transpose_split<<<dim3(256 * 512 / 256), dim3(256), 0, stream>>>(sem_w, wseh, wsel, 256, 9);
  transpose_split<<<dim3(256 * 512 / 256), dim3(256), 0, stream>>>(
      epi_w, wseh + (size_t)256 * 512, wsel + (size_t)256 * 512, 256, 9);

  for (int c = 0; c < nch; ++c) {
    const int tok0 = c * chunkN;
    // t1 = relu(embed[seq] @ w1 + b1)   (gather fused into A-staging)
    hgemm<0><<<dim3(1024 / 128, chunkN / 128), dim3(256), 0, stream>>>(
        seq, embed, nullptr, nullptr, w1th, w1tl, b1, nullptr,
        nullptr, t1h, t1l, nullptr, nullptr, 512, 1024, tok0);
    // x = embed[seq] + t1 @ w2 + b2     (exact fp32 resid from embed)
    hgemm<1><<<dim3(512 / 128, chunkN / 128), dim3(256), 0, stream>>>(
        seq, embed, t1h, t1l, w2th, w2tl, b2, nullptr,
        x, nullptr, nullptr, nullptr, nullptr, 1024, 512, tok0);
    ln_split<<<dim3(chunkN / 4), dim3(256), 0, stream>>>(x, ln_g, ln_b, hh, hl);
    // ks|ke = h @ [sem_w | epi_w] + b
    hgemm<2><<<dim3(512 / 128, chunkN / 128), dim3(256), 0, stream>>>(
        seq, embed, hh, hl, wseh, wsel, sem_b, epi_b,
        nullptr, nullptr, nullptr, ks + (size_t)tok0 * kHalf, ke + (size_t)tok0 * kHalf,
        512, 512, tok0);
  }

  scan_chunked<<<dim3(512), dim3(256), 0, stream>>>(ks, ke, wts, cout_);
  out_gemm<<<dim3(kV / 128), dim3(256), 0, stream>>>(cout_, out_w, out_b, out);

  (void)in_sizes; (void)n_in; (void)out_size;
}

// Round 7
// 1746.298 us; speedup vs baseline: 1.8893x; 1.0393x over previous
//
#include <hip/hip_runtime.h>
#include <hip/hip_bf16.h>
#include <math.h>

namespace {

constexpr int kH     = 512;
constexpr int kL     = 1024;
constexpr int kB     = 64;
constexpr int kHalf  = 256;
constexpr int kV     = 32000;
constexpr int kTok   = kB * kL;     // 65536

using f32x4 = __attribute__((ext_vector_type(4))) float;
using f16x8 = __attribute__((ext_vector_type(8))) _Float16;

__device__ inline void fsplit(float v, _Float16& h, _Float16& l) {
  h = (_Float16)v;
  l = (_Float16)(v - (float)h);
}

// ---------------- positional weights
__global__ void pos_kernel(const float* __restrict__ pos_emb,
                           const float* __restrict__ pos_w,
                           const float* __restrict__ pos_b,
                           float* __restrict__ wts)
{
  int t = blockIdx.x * blockDim.x + threadIdx.x;
  if (t >= kL) return;
  float z = pos_b[0];
#pragma unroll
  for (int p = 0; p < 16; ++p) z += pos_emb[t * 16 + p] * pos_w[p];
  wts[t] = 1.f / (1.f + expf(-z));
}

// ---------------- transpose + hi/lo fp16 split: W[K][N] fp32 -> Th/Tl[N][K]
__global__ __launch_bounds__(256) void transpose_split(
    const float* __restrict__ W, _Float16* __restrict__ Th,
    _Float16* __restrict__ Tl, int N, int kshift)
{
  const int idx = blockIdx.x * 256 + threadIdx.x;
  const int K = 1 << kshift;
  const int k = idx & (K - 1);
  const int n = idx >> kshift;
  const float w = W[(size_t)k * N + n];
  const _Float16 h = (_Float16)w;
  Th[idx] = h;
  Tl[idx] = (_Float16)(w - (float)h);
}

// ---------------- split-fp16 MFMA GEMM: C[M,N] = A[M,K] @ (Bh+Bl)[N,K]^T
template <int EPI>
__global__ __launch_bounds__(256) void hgemm(
    const int* __restrict__ seq, const float* __restrict__ embed,
    const _Float16* __restrict__ Ah, const _Float16* __restrict__ Al,
    const _Float16* __restrict__ Bh, const _Float16* __restrict__ Bl,
    const float* __restrict__ bias, const float* __restrict__ bias2,
    float* __restrict__ Xout, _Float16* __restrict__ Oh, _Float16* __restrict__ Ol,
    float* __restrict__ ks, float* __restrict__ ke,
    int K, int N, int tok0c)
{
  __shared__ _Float16 lds[4][128][40];   // Ahi, Alo, Bhi, Blo; +8 pad (80B stride)
  const int tid  = threadIdx.x;
  const int lane = tid & 63;
  const int wv   = tid >> 6;
  const int wm   = (wv >> 1) * 64;
  const int wn   = (wv & 1) * 64;
  const int bm0  = blockIdx.y * 128;
  const int bn0  = blockIdx.x * 128;

  f32x4 acc[4][4];
#pragma unroll
  for (int i = 0; i < 4; ++i)
#pragma unroll
    for (int j = 0; j < 4; ++j) acc[i][j] = {0.f, 0.f, 0.f, 0.f};

  const int sr = tid >> 1;            // staging row 0..127
  const int sc = (tid & 1) << 4;      // 0 or 16 (halves)
  const _Float16* gBh = Bh + (size_t)(bn0 + sr) * K + sc;
  const _Float16* gBl = Bl + (size_t)(bn0 + sr) * K + sc;
  const _Float16* gAh = nullptr;
  const _Float16* gAl = nullptr;
  const float*    gAe = nullptr;
  if constexpr (EPI == 0) {
    const int tokrow = seq[tok0c + bm0 + sr];
    gAe = embed + (size_t)tokrow * kH + sc;
  } else {
    gAh = Ah + (size_t)(bm0 + sr) * K + sc;
    gAl = Al + (size_t)(bm0 + sr) * K + sc;
  }

  const int lrow = lane & 15;
  const int lk   = (lane >> 4) * 8;

  for (int k0 = 0; k0 < K; k0 += 32) {
    const uint4 vC0 = *(const uint4*)(gBh + k0);
    const uint4 vC1 = *(const uint4*)(gBh + k0 + 8);
    const uint4 vD0 = *(const uint4*)(gBl + k0);
    const uint4 vD1 = *(const uint4*)(gBl + k0 + 8);
    if constexpr (EPI == 0) {
      const float4 a0 = *(const float4*)(gAe + k0);
      const float4 a1 = *(const float4*)(gAe + k0 + 4);
      const float4 a2 = *(const float4*)(gAe + k0 + 8);
      const float4 a3 = *(const float4*)(gAe + k0 + 12);
      const float vv[16] = {a0.x,a0.y,a0.z,a0.w, a1.x,a1.y,a1.z,a1.w,
                            a2.x,a2.y,a2.z,a2.w, a3.x,a3.y,a3.z,a3.w};
      union { _Float16 h[16]; uint4 u[2]; } ph, pl;
#pragma unroll
      for (int i = 0; i < 16; ++i) fsplit(vv[i], ph.h[i], pl.h[i]);
      __syncthreads();
      *(uint4*)&lds[0][sr][sc]     = ph.u[0];
      *(uint4*)&lds[0][sr][sc + 8] = ph.u[1];
      *(uint4*)&lds[1][sr][sc]     = pl.u[0];
      *(uint4*)&lds[1][sr][sc + 8] = pl.u[1];
    } else {
      const uint4 vA0 = *(const uint4*)(gAh + k0);
      const uint4 vA1 = *(const uint4*)(gAh + k0 + 8);
      const uint4 vB0 = *(const uint4*)(gAl + k0);
      const uint4 vB1 = *(const uint4*)(gAl + k0 + 8);
      __syncthreads();
      *(uint4*)&lds[0][sr][sc]     = vA0;
      *(uint4*)&lds[0][sr][sc + 8] = vA1;
      *(uint4*)&lds[1][sr][sc]     = vB0;
      *(uint4*)&lds[1][sr][sc + 8] = vB1;
    }
    *(uint4*)&lds[2][sr][sc]     = vC0;
    *(uint4*)&lds[2][sr][sc + 8] = vC1;
    *(uint4*)&lds[3][sr][sc]     = vD0;
    *(uint4*)&lds[3][sr][sc + 8] = vD1;
    __syncthreads();

    f16x8 fBh[4], fBl[4];
#pragma unroll
    for (int ni = 0; ni < 4; ++ni) {
      fBh[ni] = *(const f16x8*)&lds[2][wn + ni * 16 + lrow][lk];
      fBl[ni] = *(const f16x8*)&lds[3][wn + ni * 16 + lrow][lk];
    }
#pragma unroll
    for (int mi = 0; mi < 4; ++mi) {
      const f16x8 ah = *(const f16x8*)&lds[0][wm + mi * 16 + lrow][lk];
      const f16x8 al = *(const f16x8*)&lds[1][wm + mi * 16 + lrow][lk];
#pragma unroll
      for (int ni = 0; ni < 4; ++ni) {
        acc[mi][ni] = __builtin_amdgcn_mfma_f32_16x16x32_f16(ah, fBh[ni], acc[mi][ni], 0, 0, 0);
        acc[mi][ni] = __builtin_amdgcn_mfma_f32_16x16x32_f16(ah, fBl[ni], acc[mi][ni], 0, 0, 0);
        acc[mi][ni] = __builtin_amdgcn_mfma_f32_16x16x32_f16(al, fBh[ni], acc[mi][ni], 0, 0, 0);
      }
    }
  }

  const int erow0 = (lane >> 4) * 4;
  if constexpr (EPI == 0) {
#pragma unroll
    for (int mi = 0; mi < 4; ++mi)
#pragma unroll
      for (int ni = 0; ni < 4; ++ni) {
        const int gn = bn0 + wn + ni * 16 + (lane & 15);
        const float bv = bias[gn];
#pragma unroll
        for (int r = 0; r < 4; ++r) {
          const int gm = bm0 + wm + mi * 16 + erow0 + r;
          float v = fmaxf(acc[mi][ni][r] + bv, 0.f);
          const _Float16 h = (_Float16)v;
          Oh[(size_t)gm * N + gn] = h;
          Ol[(size_t)gm * N + gn] = (_Float16)(v - (float)h);
        }
      }
  } else if constexpr (EPI == 1) {
#pragma unroll
    for (int mi = 0; mi < 4; ++mi)
#pragma unroll
      for (int r = 0; r < 4; ++r) {
        const int gm = bm0 + wm + mi * 16 + erow0 + r;
        const int tok = seq[tok0c + gm];
        const float* er = embed + (size_t)tok * kH;
#pragma unroll
        for (int ni = 0; ni < 4; ++ni) {
          const int gn = bn0 + wn + ni * 16 + (lane & 15);
          Xout[(size_t)gm * N + gn] = acc[mi][ni][r] + bias[gn] + er[gn];
        }
      }
  } else {
#pragma unroll
    for (int mi = 0; mi < 4; ++mi)
#pragma unroll
      for (int ni = 0; ni < 4; ++ni) {
        const int gn = bn0 + wn + ni * 16 + (lane & 15);
        const float bv = (gn < 256) ? bias[gn] : bias2[gn - 256];
#pragma unroll
        for (int r = 0; r < 4; ++r) {
          const int gm = bm0 + wm + mi * 16 + erow0 + r;
          const float v = acc[mi][ni][r] + bv;
          if (gn < 256) ks[(size_t)gm * 256 + gn] = v;
          else          ke[(size_t)gm * 256 + (gn - 256)] = v;
        }
      }
  }
}

// ---------------- LayerNorm: x fp32 -> hi/lo fp16
__global__ __launch_bounds__(256) void ln_split(
    const float* __restrict__ x, const float* __restrict__ g,
    const float* __restrict__ bta, _Float16* __restrict__ hh,
    _Float16* __restrict__ hl)
{
  const int wid  = threadIdx.x >> 6;
  const int lane = threadIdx.x & 63;
  const int ltok = blockIdx.x * 4 + wid;
  const float* xp = x + (size_t)ltok * kH;
  const float4 v0 = *(const float4*)(xp + lane * 8);
  const float4 v1 = *(const float4*)(xp + lane * 8 + 4);
  float s  = v0.x + v0.y + v0.z + v0.w + v1.x + v1.y + v1.z + v1.w;
  float ss = v0.x * v0.x + v0.y * v0.y + v0.z * v0.z + v0.w * v0.w +
             v1.x * v1.x + v1.y * v1.y + v1.z * v1.z + v1.w * v1.w;
#pragma unroll
  for (int m = 1; m < 64; m <<= 1) { s += __shfl_xor(s, m); ss += __shfl_xor(ss, m); }
  const float mu  = s * (1.f / kH);
  const float var = ss * (1.f / kH) - mu * mu;
  const float rs  = 1.f / sqrtf(var + 1e-5f);
  const float4 g0 = *(const float4*)(g + lane * 8);
  const float4 g1 = *(const float4*)(g + lane * 8 + 4);
  const float4 b0 = *(const float4*)(bta + lane * 8);
  const float4 b1 = *(const float4*)(bta + lane * 8 + 4);
  const float vv[8] = {v0.x, v0.y, v0.z, v0.w, v1.x, v1.y, v1.z, v1.w};
  const float gg[8] = {g0.x, g0.y, g0.z, g0.w, g1.x, g1.y, g1.z, g1.w};
  const float bb[8] = {b0.x, b0.y, b0.z, b0.w, b1.x, b1.y, b1.z, b1.w};
  union { _Float16 h[8]; uint4 u; } ph, pl;
#pragma unroll
  for (int i = 0; i < 8; ++i) {
    const float o = (vv[i] - mu) * rs * gg[i] + bb[i];
    fsplit(o, ph.h[i], pl.h[i]);
  }
  *(uint4*)(hh + (size_t)ltok * kH + lane * 8) = ph.u;
  *(uint4*)(hl + (size_t)ltok * kH + lane * 8) = pl.u;
}

// ---------------- chunked WY delta-rule scan (v4).
// r5 structure + K-panel LDS double-buffer with straight-line register
// prefetch (NO lambda: r6's by-ref lambda forced pv into scratch -> 1.6 GB
// spill traffic), packed 16B U stores, fused invnorm.
struct PhA2 { _Float16 Kph[2][64][72], Kpl[2][64][72]; };           // 36864 B
struct PhB2 { float Rr[64][66]; _Float16 Uh[64][72], Ul[64][72]; }; // 35328 B
union  ShU1 { PhA2 a; PhB2 b; };
struct SGS  { _Float16 Sph[64][72], Spl[64][72]; };                 // 18432 B
union  ShU2 { SGS s; float Gm[64][66]; float cred[4][64]; };

__global__ __launch_bounds__(256, 2) void scan_chunked(
    const float* __restrict__ ks, const float* __restrict__ ke,
    const float* __restrict__ wts, float* __restrict__ c_out)
{
  __shared__ ShU1 u1;
  __shared__ ShU2 u2;
  __shared__ float aS[64], wS[64];

  const int tid  = threadIdx.x;
  const int lane = tid & 63;
  const int wv   = tid >> 6;
  const int l15  = lane & 15;
  const int quad = lane >> 4;
  const int wg   = blockIdx.x;
  const int b    = wg >> 3;
  const int mat  = (wg >> 2) & 1;
  const int q    = wg & 3;
  const int j0   = q * 64;
  const float* kb = (mat ? ke : ks) + (size_t)b * ((size_t)kL * kHalf);

  f32x4 S[16];
#pragma unroll
  for (int i = 0; i < 16; ++i) S[i] = {0.f, 0.f, 0.f, 0.f};

  const int stk = tid >> 2;          // staging token 0..63
  const int dg  = (tid & 3) * 16;    // staging col group
  const float* stgbase = kb + (size_t)stk * kHalf + dg;

  for (int ck = 0; ck < 16; ++ck) {
    const int tok0 = ck * 64;
    float ssq = 0.f;
    f32x4 Qa[4], Ga[4];
#pragma unroll
    for (int i = 0; i < 4; ++i) { Qa[i] = {0.f,0.f,0.f,0.f}; Ga[i] = {0.f,0.f,0.f,0.f}; }

    __syncthreads();   // B0: prev chunk's Uh/Ul readers done (Kbuf aliases)

    {  // prologue: stage K panel 0 into buf 0
      const float* src = stgbase + (size_t)tok0 * kHalf;
      const float4 v0 = *(const float4*)(src);
      const float4 v1 = *(const float4*)(src + 4);
      const float4 v2 = *(const float4*)(src + 8);
      const float4 v3 = *(const float4*)(src + 12);
      const float vv[16] = {v0.x,v0.y,v0.z,v0.w, v1.x,v1.y,v1.z,v1.w,
                            v2.x,v2.y,v2.z,v2.w, v3.x,v3.y,v3.z,v3.w};
      union { _Float16 h[16]; uint4 u[2]; } ph, pl;
#pragma unroll
      for (int i = 0; i < 16; ++i) { fsplit(vv[i], ph.h[i], pl.h[i]); ssq += vv[i]*vv[i]; }
      *(uint4*)&u1.a.Kph[0][stk][dg]     = ph.u[0];
      *(uint4*)&u1.a.Kph[0][stk][dg + 8] = ph.u[1];
      *(uint4*)&u1.a.Kpl[0][stk][dg]     = pl.u[0];
      *(uint4*)&u1.a.Kpl[0][stk][dg + 8] = pl.u[1];
    }
    if (wv == 0) {  // stage S panel 0 (rows 0..63): [col][row] hi/lo
#pragma unroll
      for (int mi = 0; mi < 4; ++mi)
#pragma unroll
        for (int nt = 0; nt < 4; ++nt) {
          const f32x4 v = S[mi * 4 + nt];
          union { _Float16 h[4]; uint2 u; } qh, ql;
#pragma unroll
          for (int r = 0; r < 4; ++r) fsplit(v[r], qh.h[r], ql.h[r]);
          *(uint2*)&u2.s.Sph[nt * 16 + l15][mi * 16 + quad * 4] = qh.u;
          *(uint2*)&u2.s.Spl[nt * 16 + l15][mi * 16 + quad * 4] = ql.u;
        }
    }
    __syncthreads();   // B1

    for (int p = 0; p < 4; ++p) {
      const int cur = p & 1;
      float4 pv0, pv1, pv2, pv3;     // next-panel prefetch, plain registers
      if (p < 3) {
        const float* src = stgbase + (size_t)tok0 * kHalf + (p + 1) * 64;
        pv0 = *(const float4*)(src);
        pv1 = *(const float4*)(src + 4);
        pv2 = *(const float4*)(src + 8);
        pv3 = *(const float4*)(src + 12);
      }
#pragma unroll
      for (int kit = 0; kit < 2; ++kit) {
        const int ko = kit * 32 + quad * 8;
        const f16x8 ah = *(const f16x8*)&u1.a.Kph[cur][wv * 16 + l15][ko];
        const f16x8 al = *(const f16x8*)&u1.a.Kpl[cur][wv * 16 + l15][ko];
#pragma unroll
        for (int nt = 0; nt < 4; ++nt) {
          const f16x8 bh = *(const f16x8*)&u2.s.Sph[nt * 16 + l15][ko];
          const f16x8 bl = *(const f16x8*)&u2.s.Spl[nt * 16 + l15][ko];
          Qa[nt] = __builtin_amdgcn_mfma_f32_16x16x32_f16(ah, bh, Qa[nt], 0, 0, 0);
          Qa[nt] = __builtin_amdgcn_mfma_f32_16x16x32_f16(ah, bl, Qa[nt], 0, 0, 0);
          Qa[nt] = __builtin_amdgcn_mfma_f32_16x16x32_f16(al, bh, Qa[nt], 0, 0, 0);
        }
#pragma unroll
        for (int nt = 0; nt < 4; ++nt) {
          const f16x8 bh = *(const f16x8*)&u1.a.Kph[cur][nt * 16 + l15][ko];
          const f16x8 bl = *(const f16x8*)&u1.a.Kpl[cur][nt * 16 + l15][ko];
          Ga[nt] = __builtin_amdgcn_mfma_f32_16x16x32_f16(ah, bh, Ga[nt], 0, 0, 0);
          Ga[nt] = __builtin_amdgcn_mfma_f32_16x16x32_f16(ah, bl, Ga[nt], 0, 0, 0);
          Ga[nt] = __builtin_amdgcn_mfma_f32_16x16x32_f16(al, bh, Ga[nt], 0, 0, 0);
        }
      }
      __syncthreads();   // B2: Sbuf + Kbuf[cur] reads done
      if (p < 3) {
        const float vv[16] = {pv0.x,pv0.y,pv0.z,pv0.w, pv1.x,pv1.y,pv1.z,pv1.w,
                              pv2.x,pv2.y,pv2.z,pv2.w, pv3.x,pv3.y,pv3.z,pv3.w};
        union { _Float16 h[16]; uint4 u[2]; } ph, pl;
#pragma unroll
        for (int i = 0; i < 16; ++i) { fsplit(vv[i], ph.h[i], pl.h[i]); ssq += vv[i]*vv[i]; }
        *(uint4*)&u1.a.Kph[1 - cur][stk][dg]     = ph.u[0];
        *(uint4*)&u1.a.Kph[1 - cur][stk][dg + 8] = ph.u[1];
        *(uint4*)&u1.a.Kpl[1 - cur][stk][dg]     = pl.u[0];
        *(uint4*)&u1.a.Kpl[1 - cur][stk][dg + 8] = pl.u[1];
        if (wv == p + 1) {  // stage S panel p+1
#pragma unroll
          for (int mi = 0; mi < 4; ++mi)
#pragma unroll
            for (int nt = 0; nt < 4; ++nt) {
              const f32x4 v = S[mi * 4 + nt];
              union { _Float16 h[4]; uint2 u; } qh, ql;
#pragma unroll
              for (int r = 0; r < 4; ++r) fsplit(v[r], qh.h[r], ql.h[r]);
              *(uint2*)&u2.s.Sph[nt * 16 + l15][mi * 16 + quad * 4] = qh.u;
              *(uint2*)&u2.s.Spl[nt * 16 + l15][mi * 16 + quad * 4] = ql.u;
            }
        }
        __syncthreads();   // B3
      }
    }

    // fused invnorm
    ssq += __shfl_xor(ssq, 1);
    ssq += __shfl_xor(ssq, 2);
    if ((tid & 3) == 0) {
      const float w = mat ? wts[tok0 + stk] : 1.f;
      wS[stk] = w;
      aS[stk] = w / (ssq + 1e-6f);
    }

    // Q -> Rr[t][col] ; G -> Gm  (aliased regions; B2(p=3) separated reads)
#pragma unroll
    for (int nt = 0; nt < 4; ++nt) {
#pragma unroll
      for (int r = 0; r < 4; ++r)
        u1.b.Rr[wv * 16 + quad * 4 + r][nt * 16 + l15] = Qa[nt][r];
      *(float4*)&u2.Gm[nt * 16 + l15][wv * 16 + quad * 4] = *(const float4*)&Ga[nt];
    }
    // prefetch S-update A-fragments (K^T), consumed after the solve
    f16x8 uah[8], ual[8];
#pragma unroll
    for (int mi = 0; mi < 4; ++mi)
#pragma unroll
      for (int kit = 0; kit < 2; ++kit) {
        union { _Float16 h[8]; f16x8 v; } Ph, Pl;
        const int drow = 64 * wv + mi * 16 + l15;
#pragma unroll
        for (int jj = 0; jj < 8; ++jj) {
          const float v = kb[(size_t)(tok0 + kit * 32 + quad * 8 + jj) * kHalf + drow];
          fsplit(v, Ph.h[jj], Pl.h[jj]);
        }
        uah[mi * 2 + kit] = Ph.v;
        ual[mi * 2 + kit] = Pl.v;
      }
    __syncthreads();   // B4: Rr/Gm/aS/wS visible

    // barrier-free triangular solve: thread j owns col j
    if (tid < 64) {
      const int j = tid;
      for (int blk = 0; blk < 8; ++blk) {
        const int t0 = blk * 8;
        float rl[8], kv[8], ub[8];
#pragma unroll
        for (int i = 0; i < 8; ++i) rl[i] = u1.b.Rr[t0 + i][j];
#pragma unroll
        for (int i = 0; i < 8; ++i)
          kv[i] = kb[(size_t)(tok0 + t0 + i) * kHalf + j0 + j];
#pragma unroll
        for (int i = 0; i < 8; ++i) {
          const int t = t0 + i;
          float u = wS[t] * kv[i] - aS[t] * rl[i];
          if (ck == 15 && t == 63) u = 0.f;   // token L-1 is the query only
          ub[i] = u;
#pragma unroll
          for (int i2 = i + 1; i2 < 8; ++i2) rl[i2] += u2.Gm[t0 + i2][t] * u;
        }
        union { _Float16 h[8]; uint4 u4; } uh, ul;
#pragma unroll
        for (int i = 0; i < 8; ++i) fsplit(ub[i], uh.h[i], ul.h[i]);
        *(uint4*)&u1.b.Uh[j][t0] = uh.u4;    // 16B packed: conflict-free
        *(uint4*)&u1.b.Ul[j][t0] = ul.u4;
        for (int t2 = t0 + 8; t2 < 64; ++t2) {
          const float4 g0 = *(const float4*)&u2.Gm[t2][t0];
          const float4 g1 = *(const float4*)&u2.Gm[t2][t0 + 4];
          u1.b.Rr[t2][j] += g0.x*ub[0] + g0.y*ub[1] + g0.z*ub[2] + g0.w*ub[3]
                          + g1.x*ub[4] + g1.y*ub[5] + g1.z*ub[6] + g1.w*ub[7];
        }
      }
    }
    __syncthreads();   // B5: Uh/Ul visible

    // S += K^T U
#pragma unroll
    for (int kit = 0; kit < 2; ++kit) {
      const int ko = kit * 32 + quad * 8;
#pragma unroll
      for (int nt = 0; nt < 4; ++nt) {
        const f16x8 bh = *(const f16x8*)&u1.b.Uh[nt * 16 + l15][ko];
        const f16x8 bl = *(const f16x8*)&u1.b.Ul[nt * 16 + l15][ko];
#pragma unroll
        for (int mi = 0; mi < 4; ++mi) {
          f32x4 s = S[mi * 4 + nt];
          s = __builtin_amdgcn_mfma_f32_16x16x32_f16(uah[mi * 2 + kit], bh, s, 0, 0, 0);
          s = __builtin_amdgcn_mfma_f32_16x16x32_f16(uah[mi * 2 + kit], bl, s, 0, 0, 0);
          s = __builtin_amdgcn_mfma_f32_16x16x32_f16(ual[mi * 2 + kit], bh, s, 0, 0, 0);
          S[mi * 4 + nt] = s;
        }
      }
    }
  }

  // readout: c[col] = sum_rows S[row][col] * k_last[row]
  float part[4] = {0.f, 0.f, 0.f, 0.f};
#pragma unroll
  for (int mi = 0; mi < 4; ++mi) {
    float klr[4];
#pragma unroll
    for (int r = 0; r < 4; ++r)
      klr[r] = kb[(size_t)(kL - 1) * kHalf + 64 * wv + mi * 16 + quad * 4 + r];
#pragma unroll
    for (int nt = 0; nt < 4; ++nt)
#pragma unroll
      for (int r = 0; r < 4; ++r) part[nt] += S[mi * 4 + nt][r] * klr[r];
  }
#pragma unroll
  for (int nt = 0; nt < 4; ++nt) {
    part[nt] += __shfl_xor(part[nt], 16);
    part[nt] += __shfl_xor(part[nt], 32);
  }
  __syncthreads();   // all prior LDS reads done before cred aliases Gm/Sbuf
  if (lane < 16) {
#pragma unroll
    for (int nt = 0; nt < 4; ++nt) u2.cred[wv][nt * 16 + l15] = part[nt];
  }
  __syncthreads();
  if (tid < 64) {
    const float c = u2.cred[0][tid] + u2.cred[1][tid] + u2.cred[2][tid] + u2.cred[3][tid];
    c_out[(size_t)b * 512 + mat * 256 + j0 + tid] = c;
  }
}

// ---------------- output GEMM: (64 x 512) @ (512 x 32000) + out_b -> fp32
__global__ __launch_bounds__(256) void out_gemm(
    const float* __restrict__ A, const float* __restrict__ Bm,
    const float* __restrict__ bias, float* __restrict__ C)
{
  __shared__ float As[16][64];
  __shared__ float Bs[16][128];
  const int tid = threadIdx.x;
  const int bn0 = blockIdx.x * 128;
  const int tm = tid >> 4, tn = tid & 15;
  float acc[4][8];
#pragma unroll
  for (int i = 0; i < 4; ++i)
#pragma unroll
    for (int j = 0; j < 8; ++j) acc[i][j] = 0.f;

  const int am  = tid & 63;
  const int ak  = (tid >> 6) * 4;
  const int bkr = tid >> 5;
  const int bcg = (tid & 31) * 4;

  for (int k0 = 0; k0 < kH; k0 += 16) {
    const float4 a0 = *(const float4*)(A + (size_t)am * kH + k0 + ak);
    const float4 b0 = *(const float4*)(Bm + (size_t)(k0 + bkr) * kV + bn0 + bcg);
    const float4 b1 = *(const float4*)(Bm + (size_t)(k0 + bkr + 8) * kV + bn0 + bcg);
    __syncthreads();
    As[ak + 0][am] = a0.x; As[ak + 1][am] = a0.y;
    As[ak + 2][am] = a0.z; As[ak + 3][am] = a0.w;
    *(float4*)&Bs[bkr][bcg]     = b0;
    *(float4*)&Bs[bkr + 8][bcg] = b1;
    __syncthreads();
#pragma unroll
    for (int kk = 0; kk < 16; ++kk) {
      const float4 aA = *(const float4*)&As[kk][tm * 4];
      const float4 bA = *(const float4*)&Bs[kk][tn * 4];
      const float4 bB = *(const float4*)&Bs[kk][64 + tn * 4];
      const float av[4] = {aA.x, aA.y, aA.z, aA.w};
      const float bv[8] = {bA.x, bA.y, bA.z, bA.w, bB.x, bB.y, bB.z, bB.w};
#pragma unroll
      for (int i = 0; i < 4; ++i)
#pragma unroll
        for (int j = 0; j < 8; ++j) acc[i][j] += av[i] * bv[j];
    }
  }

#pragma unroll
  for (int i = 0; i < 4; ++i) {
    const int row = tm * 4 + i;
#pragma unroll
    for (int hh = 0; hh < 2; ++hh) {
      const int n0 = bn0 + tn * 4 + hh * 64;
      const float4 bb = *(const float4*)(bias + n0);
      float4 o;
      o.x = acc[i][hh * 4 + 0] + bb.x;
      o.y = acc[i][hh * 4 + 1] + bb.y;
      o.z = acc[i][hh * 4 + 2] + bb.z;
      o.w = acc[i][hh * 4 + 3] + bb.w;
      *(float4*)(C + (size_t)row * kV + n0) = o;
    }
  }
}

}  // namespace

extern "C" void kernel_launch(void* const* d_in, const int* in_sizes, int n_in,
                              void* d_out, int out_size, void* d_ws, size_t ws_size,
                              hipStream_t stream)
{
  const int*   seq     = (const int*)  d_in[0];
  const float* embed   = (const float*)d_in[1];
  const float* w1      = (const float*)d_in[2];
  const float* b1      = (const float*)d_in[3];
  const float* w2      = (const float*)d_in[4];
  const float* b2      = (const float*)d_in[5];
  const float* ln_g    = (const float*)d_in[6];
  const float* ln_b    = (const float*)d_in[7];
  const float* sem_w   = (const float*)d_in[8];
  const float* sem_b   = (const float*)d_in[9];
  const float* epi_w   = (const float*)d_in[10];
  const float* epi_b   = (const float*)d_in[11];
  const float* out_w   = (const float*)d_in[12];
  const float* out_b   = (const float*)d_in[13];
  const float* pos_emb = (const float*)d_in[14];
  const float* pos_w   = (const float*)d_in[15];
  const float* pos_b   = (const float*)d_in[16];
  float* out = (float*)d_out;

  // chunk size: 16384 needs 240.3 MB of ws; fall back to 8192 if tight.
  // ws_size is constant per process -> deterministic, graph-capture-safe.
  const int chunkN = (ws_size >= (size_t)240500000) ? 16384 : 8192;
  const int nch    = kTok / chunkN;

  char* p = (char*)d_ws;
  _Float16* w1th = (_Float16*)p; p += (size_t)1024 * 512 * 2;
  _Float16* w1tl = (_Float16*)p; p += (size_t)1024 * 512 * 2;
  _Float16* w2th = (_Float16*)p; p += (size_t)512 * 1024 * 2;
  _Float16* w2tl = (_Float16*)p; p += (size_t)512 * 1024 * 2;
  _Float16* wseh = (_Float16*)p; p += (size_t)512 * 512 * 2;
  _Float16* wsel = (_Float16*)p; p += (size_t)512 * 512 * 2;
  _Float16* t1h  = (_Float16*)p; p += (size_t)chunkN * 1024 * 2;
  _Float16* t1l  = (_Float16*)p; p += (size_t)chunkN * 1024 * 2;
  float*    x    = (float*)p;    p += (size_t)chunkN * kH * 4;
  float*    ks   = (float*)p;    p += (size_t)kTok * kHalf * 4;
  float*    ke   = (float*)p;    p += (size_t)kTok * kHalf * 4;
  float*    wts  = (float*)p;    p += (size_t)kL * 4;
  float*    cout_= (float*)p;    p += (size_t)kB * 512 * 4;
  _Float16* hh   = t1h;          // alias: t1 dead once x is written
  _Float16* hl   = t1l;

  pos_kernel<<<dim3((kL + 255) / 256), dim3(256), 0, stream>>>(pos_emb, pos_w, pos_b, wts);
  transpose_split<<<dim3(1024 * 512 / 256), dim3(256), 0, stream>>>(w1, w1th, w1tl, 1024, 9);
  transpose_split<<<dim3(512 * 1024 / 256), dim3(256), 0, stream>>>(w2, w2th, w2tl, 512, 10);
  transpose_split<<<dim3(256 * 512 / 256), dim3(256), 0, stream>>>(sem_w, wseh, wsel, 256, 9);
  transpose_split<<<dim3(256 * 512 / 256), dim3(256), 0, stream>>>(
      epi_w, wseh + (size_t)256 * 512, wsel + (size_t)256 * 512, 256, 9);

  for (int c = 0; c < nch; ++c) {
    const int tok0 = c * chunkN;
    hgemm<0><<<dim3(1024 / 128, chunkN / 128), dim3(256), 0, stream>>>(
        seq, embed, nullptr, nullptr, w1th, w1tl, b1, nullptr,
        nullptr, t1h, t1l, nullptr, nullptr, 512, 1024, tok0);
    hgemm<1><<<dim3(512 / 128, chunkN / 128), dim3(256), 0, stream>>>(
        seq, embed, t1h, t1l, w2th, w2tl, b2, nullptr,
        x, nullptr, nullptr, nullptr, nullptr, 1024, 512, tok0);
    ln_split<<<dim3(chunkN / 4), dim3(256), 0, stream>>>(x, ln_g, ln_b, hh, hl);
    hgemm<2><<<dim3(512 / 128, chunkN / 128), dim3(256), 0, stream>>>(
        seq, embed, hh, hl, wseh, wsel, sem_b, epi_b,
        nullptr, nullptr, nullptr, ks + (size_t)tok0 * kHalf, ke + (size_t)tok0 * kHalf,
        512, 512, tok0);
  }

  scan_chunked<<<dim3(512), dim3(256), 0, stream>>>(ks, ke, wts, cout_);
  out_gemm<<<dim3(kV / 128), dim3(256), 0, stream>>>(cout_, out_w, out_b, out);

  (void)in_sizes; (void)n_in; (void)out_size;
}